// Round 1
// baseline (918.542 us; speedup 1.0000x reference)
//
#include <hip/hip_runtime.h>
#include <stdint.h>

#define S_DIM 2048
#define B_DIM 2
#define D_DIM 2048
#define H_DIM 16
#define C_DIM 128
#define M_DIM 4096   // S*B rows, row = s*B + b

typedef __bf16 bf16x8 __attribute__((ext_vector_type(8)));
typedef float f32x4 __attribute__((ext_vector_type(4)));
typedef unsigned short u16x8 __attribute__((ext_vector_type(8)));

__device__ __forceinline__ float bf2f(unsigned short u) {
    union { unsigned int i; float f; } c; c.i = ((unsigned int)u) << 16; return c.f;
}
__device__ __forceinline__ unsigned short f2bf(float f) {
    union { float f; unsigned int i; } c; c.f = f;
    unsigned int r = c.i + 0x7FFFu + ((c.i >> 16) & 1u);  // RTN-even
    return (unsigned short)(r >> 16);
}

// ---------------- cos/sin tables for RoPE ----------------
__global__ void rope_tables_k(const float* __restrict__ freqs,
                              float* __restrict__ ctab, float* __restrict__ stab, int n) {
    int i = blockIdx.x * blockDim.x + threadIdx.x;
    if (i < n) { float f = freqs[i]; ctab[i] = cosf(f); stab[i] = sinf(f); }
}

// ---------------- fp32 -> bf16 cast (vectorized) ----------------
__global__ void cast_bf16_k(const float* __restrict__ in, unsigned short* __restrict__ out, int n4) {
    int stride = gridDim.x * blockDim.x;
    for (int i = blockIdx.x * blockDim.x + threadIdx.x; i < n4; i += stride) {
        float4 v = reinterpret_cast<const float4*>(in)[i];
        ushort4 o;
        o.x = f2bf(v.x); o.y = f2bf(v.y); o.z = f2bf(v.z); o.w = f2bf(v.w);
        reinterpret_cast<ushort4*>(out)[i] = o;
    }
}

// ---------------- GEMM: C[M,N] = A[M,K] * B[N,K]^T  (both bf16, K-contiguous) ----
// 128x128 tile, BK=32, 4 waves (2x2), 4x4 16x16x32 MFMA fragments per wave.
// global_load_lds width=16 staging, linear LDS (m97 structure).
template <typename OutT>
__global__ __launch_bounds__(256) void gemm_bt_k(
    const unsigned short* __restrict__ A,
    const unsigned short* __restrict__ Bm,
    OutT* __restrict__ C,
    int M, int N, int K)
{
    constexpr int BK = 32;
    __shared__ __align__(16) unsigned short ldsA[128 * BK];
    __shared__ __align__(16) unsigned short ldsB[128 * BK];

    const int tid  = threadIdx.x;
    const int wave = tid >> 6;
    const int lane = tid & 63;
    const int brow = blockIdx.x * 128;
    const int bcol = blockIdx.y * 128;
    const int wr = (wave >> 1) * 64;   // wave row offset in tile
    const int wc = (wave & 1) * 64;    // wave col offset in tile

    f32x4 acc[4][4] = {};

    const int kc = (lane & 3) * 8;     // k element offset for staging lane

    for (int kt = 0; kt < K; kt += BK) {
        __syncthreads();
        #pragma unroll
        for (int j = 0; j < 2; ++j) {
            const int i = wave * 2 + j;                 // 8 wave-instructions, 1KB each
            const int r = i * 16 + (lane >> 2);         // tile row staged by this lane
            __builtin_amdgcn_global_load_lds(
                (const __attribute__((address_space(1))) void*)(A + (size_t)(brow + r) * K + kt + kc),
                (__attribute__((address_space(3))) void*)(ldsA + i * 512),
                16, 0, 0);
            __builtin_amdgcn_global_load_lds(
                (const __attribute__((address_space(1))) void*)(Bm + (size_t)(bcol + r) * K + kt + kc),
                (__attribute__((address_space(3))) void*)(ldsB + i * 512),
                16, 0, 0);
        }
        __syncthreads();

        const int ro = lane & 15;
        const int ko = (lane >> 4) * 8;
        bf16x8 af[4], bfr[4];
        #pragma unroll
        for (int mi = 0; mi < 4; ++mi)
            af[mi] = *reinterpret_cast<const bf16x8*>(ldsA + (wr + mi * 16 + ro) * BK + ko);
        #pragma unroll
        for (int ni = 0; ni < 4; ++ni)
            bfr[ni] = *reinterpret_cast<const bf16x8*>(ldsB + (wc + ni * 16 + ro) * BK + ko);
        #pragma unroll
        for (int mi = 0; mi < 4; ++mi)
            #pragma unroll
            for (int ni = 0; ni < 4; ++ni)
                acc[mi][ni] = __builtin_amdgcn_mfma_f32_16x16x32_bf16(af[mi], bfr[ni], acc[mi][ni], 0, 0, 0);
    }

    // epilogue: C/D layout col=lane&15, row=(lane>>4)*4+reg  (m89-verified)
    const int ro = lane & 15;
    const int rg = (lane >> 4) * 4;
    #pragma unroll
    for (int mi = 0; mi < 4; ++mi) {
        #pragma unroll
        for (int r = 0; r < 4; ++r) {
            const int row = brow + wr + mi * 16 + rg + r;
            const size_t base = (size_t)row * N + bcol + wc;
            #pragma unroll
            for (int ni = 0; ni < 4; ++ni) {
                float v = acc[mi][ni][r];
                if constexpr (sizeof(OutT) == 2) C[base + ni * 16 + ro] = f2bf(v);
                else                             C[base + ni * 16 + ro] = v;
            }
        }
    }
}

// ---------------- per-head RMSNorm + RoPE on Q/K, relayout to [b*H+h][s][c] ----
// one wave per (m=s*B+b, h); 2 channels per lane (c = 2*lane, 2*lane+1)
__global__ __launch_bounds__(256) void qk_post_k(
    const unsigned short* __restrict__ raw,   // [M][ld], head h at col h*C
    int ld,
    const float* __restrict__ wscale,         // [C]
    const float* __restrict__ ctab, const float* __restrict__ stab, // [S][C]
    unsigned short* __restrict__ outp)        // [B*H][S][C]
{
    const int gw = blockIdx.x * 4 + (threadIdx.x >> 6);
    const int lane = threadIdx.x & 63;
    const int m = gw >> 4;          // row in [0, M)
    const int h = gw & 15;
    const int s = m >> 1, b = m & 1;
    const int c0 = lane * 2;

    const unsigned short* src = raw + (size_t)m * ld + h * C_DIM + c0;
    unsigned int packed = *reinterpret_cast<const unsigned int*>(src);
    float x0 = bf2f((unsigned short)(packed & 0xFFFF));
    float x1 = bf2f((unsigned short)(packed >> 16));

    float ss = x0 * x0 + x1 * x1;
    #pragma unroll
    for (int off = 32; off; off >>= 1) ss += __shfl_xor(ss, off);
    const float rs = rsqrtf(ss * (1.0f / C_DIM) + 1e-6f);

    float n0 = x0 * rs * wscale[c0];
    float n1 = x1 * rs * wscale[c0 + 1];
    // RoPE: partner channel c +/- 64 lives in lane^32
    float p0 = __shfl_xor(n0, 32);
    float p1 = __shfl_xor(n1, 32);
    const float sgn = (lane < 32) ? -1.0f : 1.0f;
    const float* cp = ctab + (size_t)s * C_DIM + c0;
    const float* sp = stab + (size_t)s * C_DIM + c0;
    float o0 = n0 * cp[0] + sgn * p0 * sp[0];
    float o1 = n1 * cp[1] + sgn * p1 * sp[1];

    unsigned int opk = (unsigned int)f2bf(o0) | ((unsigned int)f2bf(o1) << 16);
    *reinterpret_cast<unsigned int*>(
        outp + ((size_t)(b * H_DIM + h) * S_DIM + s) * C_DIM + c0) = opk;
}

// ---------------- V relayout+transpose: raw [M][ld] (V at col 2*D) -> Vt [b*H+h][C][S] ----
__global__ __launch_bounds__(256) void v_transpose_k(
    const unsigned short* __restrict__ raw, int ld, int colbase,
    unsigned short* __restrict__ Vt)
{
    __shared__ __align__(16) unsigned short tile[64][136];  // +8 pad
    const int bh = blockIdx.y;
    const int b = bh >> 4, h = bh & 15;
    const int sbase = blockIdx.x * 64;
    const int t = threadIdx.x;

    {   // load 64 s-rows x 128 c, coalesced 16B
        const int s = t >> 2, cq = (t & 3) * 32;
        const unsigned short* src = raw + (size_t)((sbase + s) * B_DIM + b) * ld + colbase + h * C_DIM + cq;
        #pragma unroll
        for (int j = 0; j < 4; ++j) {
            u16x8 v = *reinterpret_cast<const u16x8*>(src + j * 8);
            *reinterpret_cast<u16x8*>(&tile[s][cq + j * 8]) = v;
        }
    }
    __syncthreads();
    {   // write 128 c-rows x 64 s, coalesced 16B
        const int c = t >> 1, sh = (t & 1) * 32;
        unsigned short* dst = Vt + ((size_t)bh * C_DIM + c) * S_DIM + sbase + sh;
        #pragma unroll
        for (int j = 0; j < 32; j += 8) {
            u16x8 o;
            #pragma unroll
            for (int e = 0; e < 8; ++e) o[e] = tile[sh + j + e][c];
            *reinterpret_cast<u16x8*>(dst + j) = o;
        }
    }
}

// ---------------- flash attention: Q[bh][S][C] x K[bh][S][C] -> P -> x Vt[bh][C][S] ----
// grid (S/64, B*H); 4 waves/block, each wave owns 16 q-rows; KT=32 per iteration.
__global__ __launch_bounds__(256) void attn_k(
    const unsigned short* __restrict__ Qb,
    const unsigned short* __restrict__ Kb,
    const unsigned short* __restrict__ Vt,
    unsigned short* __restrict__ Ao)          // [M][D], row = s*B+b, col = h*C+c
{
    __shared__ __align__(16) unsigned short plds[4][16][40];  // per-wave P tile, +8 pad
    const int bh = blockIdx.y;
    const int wave = threadIdx.x >> 6;
    const int lane = threadIdx.x & 63;
    const int qbase = blockIdx.x * 64 + wave * 16;
    const int ro = lane & 15;
    const int ko = (lane >> 4) * 8;
    const int rg = (lane >> 4) * 4;

    const unsigned short* Q  = Qb + (size_t)bh * S_DIM * C_DIM;
    const unsigned short* Km = Kb + (size_t)bh * S_DIM * C_DIM;
    const unsigned short* V  = Vt + (size_t)bh * C_DIM * S_DIM;

    bf16x8 qf[4];
    #pragma unroll
    for (int kf = 0; kf < 4; ++kf)
        qf[kf] = *reinterpret_cast<const bf16x8*>(Q + (size_t)(qbase + ro) * C_DIM + kf * 32 + ko);

    f32x4 of[8] = {};
    float mrow[4] = {-1e30f, -1e30f, -1e30f, -1e30f};
    float lrow[4] = {0.f, 0.f, 0.f, 0.f};
    const float inv_scale = 0.08838834764831845f;  // 1/sqrt(128)

    for (int kb = 0; kb < S_DIM; kb += 32) {
        f32x4 sc[2] = {};
        #pragma unroll
        for (int nc = 0; nc < 2; ++nc)
            #pragma unroll
            for (int kf = 0; kf < 4; ++kf) {
                bf16x8 kfr = *reinterpret_cast<const bf16x8*>(
                    Km + (size_t)(kb + nc * 16 + ro) * C_DIM + kf * 32 + ko);
                sc[nc] = __builtin_amdgcn_mfma_f32_16x16x32_bf16(qf[kf], kfr, sc[nc], 0, 0, 0);
            }
        float mx[4];
        #pragma unroll
        for (int r = 0; r < 4; ++r) {
            sc[0][r] *= inv_scale; sc[1][r] *= inv_scale;
            mx[r] = fmaxf(sc[0][r], sc[1][r]);
        }
        #pragma unroll
        for (int off = 1; off < 16; off <<= 1)
            #pragma unroll
            for (int r = 0; r < 4; ++r) mx[r] = fmaxf(mx[r], __shfl_xor(mx[r], off));

        float rescale[4], ladd[4];
        #pragma unroll
        for (int r = 0; r < 4; ++r) {
            float mnew = fmaxf(mrow[r], mx[r]);
            rescale[r] = __expf(mrow[r] - mnew);
            mrow[r] = mnew;
            float p0 = __expf(sc[0][r] - mnew);
            float p1 = __expf(sc[1][r] - mnew);
            sc[0][r] = p0; sc[1][r] = p1;
            ladd[r] = p0 + p1;
        }
        #pragma unroll
        for (int off = 1; off < 16; off <<= 1)
            #pragma unroll
            for (int r = 0; r < 4; ++r) ladd[r] += __shfl_xor(ladd[r], off);
        #pragma unroll
        for (int r = 0; r < 4; ++r) lrow[r] = lrow[r] * rescale[r] + ladd[r];
        #pragma unroll
        for (int nf = 0; nf < 8; ++nf)
            #pragma unroll
            for (int r = 0; r < 4; ++r) of[nf][r] *= rescale[r];

        // P (f32 frag layout) -> LDS -> A-operand frag layout
        #pragma unroll
        for (int nc = 0; nc < 2; ++nc)
            #pragma unroll
            for (int r = 0; r < 4; ++r)
                plds[wave][rg + r][nc * 16 + ro] = f2bf(sc[nc][r]);
        __asm__ volatile("" ::: "memory");  // order LDS write -> read (same wave, lockstep)
        bf16x8 pa = *reinterpret_cast<const bf16x8*>(&plds[wave][ro][ko]);

        #pragma unroll
        for (int nf = 0; nf < 8; ++nf) {
            bf16x8 vf = *reinterpret_cast<const bf16x8*>(
                V + (size_t)(nf * 16 + ro) * S_DIM + kb + ko);
            of[nf] = __builtin_amdgcn_mfma_f32_16x16x32_bf16(pa, vf, of[nf], 0, 0, 0);
        }
    }

    const int b = bh >> 4, h = bh & 15;
    float inv_l[4];
    #pragma unroll
    for (int r = 0; r < 4; ++r) inv_l[r] = 1.0f / lrow[r];
    #pragma unroll
    for (int r = 0; r < 4; ++r) {
        const int srow = qbase + rg + r;
        unsigned short* dst = Ao + (size_t)(srow * B_DIM + b) * D_DIM + h * C_DIM;
        #pragma unroll
        for (int nf = 0; nf < 8; ++nf)
            dst[nf * 16 + ro] = f2bf(of[nf][r] * inv_l[r]);
    }
}

extern "C" void kernel_launch(void* const* d_in, const int* in_sizes, int n_in,
                              void* d_out, int out_size, void* d_ws, size_t ws_size,
                              hipStream_t stream) {
    const float* x       = (const float*)d_in[0];
    const float* rope    = (const float*)d_in[1];
    const float* Wq      = (const float*)d_in[2];
    const float* Wk      = (const float*)d_in[3];
    const float* Wv      = (const float*)d_in[4];
    const float* Wo      = (const float*)d_in[5];
    const float* q_scale = (const float*)d_in[6];
    const float* k_scale = (const float*)d_in[7];
    float* out = (float*)d_out;

    char* w = (char*)d_ws;
    size_t off = 0;
    auto alloc = [&](size_t bytes) {
        char* p = w + off; off += (bytes + 255) & ~(size_t)255; return p;
    };
    unsigned short* xb   = (unsigned short*)alloc((size_t)M_DIM * D_DIM * 2);  // 16 MiB
    unsigned short* Wqb  = (unsigned short*)alloc((size_t)D_DIM * D_DIM * 2);  // contiguous
    unsigned short* Wkb  = (unsigned short*)alloc((size_t)D_DIM * D_DIM * 2);  //   Wq|Wk|Wv
    unsigned short* Wvb  = (unsigned short*)alloc((size_t)D_DIM * D_DIM * 2);
    unsigned short* Wob  = (unsigned short*)alloc((size_t)D_DIM * D_DIM * 2);
    unsigned short* rawQKV = (unsigned short*)alloc((size_t)M_DIM * 3 * D_DIM * 2); // [M][6144]
    unsigned short* Qb   = (unsigned short*)alloc((size_t)M_DIM * D_DIM * 2);
    unsigned short* Kb   = (unsigned short*)alloc((size_t)M_DIM * D_DIM * 2);
    unsigned short* Vt   = (unsigned short*)alloc((size_t)M_DIM * D_DIM * 2);
    float* ctab = (float*)alloc((size_t)S_DIM * C_DIM * 4);
    float* stab = (float*)alloc((size_t)S_DIM * C_DIM * 4);
    unsigned short* Ao = rawQKV;  // reuse (rawQKV dead before attention writes)
    (void)Wkb; (void)Wvb; (void)ws_size; (void)in_sizes; (void)n_in; (void)out_size;

    const int NQKV = 3 * D_DIM;  // 6144

    rope_tables_k<<<(S_DIM * C_DIM + 255) / 256, 256, 0, stream>>>(rope, ctab, stab, S_DIM * C_DIM);
    cast_bf16_k<<<1024, 256, 0, stream>>>(x,  xb,  M_DIM * D_DIM / 4);
    cast_bf16_k<<<1024, 256, 0, stream>>>(Wq, Wqb, D_DIM * D_DIM / 4);
    cast_bf16_k<<<1024, 256, 0, stream>>>(Wk, Wkb, D_DIM * D_DIM / 4);
    cast_bf16_k<<<1024, 256, 0, stream>>>(Wv, Wvb, D_DIM * D_DIM / 4);
    cast_bf16_k<<<1024, 256, 0, stream>>>(Wo, Wob, D_DIM * D_DIM / 4);

    // fused QKV projection: [4096,2048] x [6144,2048]^T
    gemm_bt_k<unsigned short><<<dim3(M_DIM / 128, NQKV / 128), 256, 0, stream>>>(
        xb, Wqb, rawQKV, M_DIM, NQKV, D_DIM);

    qk_post_k<<<M_DIM * H_DIM / 4, 256, 0, stream>>>(rawQKV,              NQKV, q_scale, ctab, stab, Qb);
    qk_post_k<<<M_DIM * H_DIM / 4, 256, 0, stream>>>(rawQKV + D_DIM,      NQKV, k_scale, ctab, stab, Kb);
    v_transpose_k<<<dim3(S_DIM / 64, B_DIM * H_DIM), 256, 0, stream>>>(rawQKV, NQKV, 2 * D_DIM, Vt);

    attn_k<<<dim3(S_DIM / 64, B_DIM * H_DIM), 256, 0, stream>>>(Qb, Kb, Vt, Ao);

    // out projection: [4096,2048] x [2048,2048]^T -> fp32 d_out
    gemm_bt_k<float><<<dim3(M_DIM / 128, D_DIM / 128), 256, 0, stream>>>(
        Ao, Wob, out, M_DIM, D_DIM, D_DIM);
}

// Round 2
// 413.453 us; speedup vs baseline: 2.2216x; 2.2216x over previous
//
#include <hip/hip_runtime.h>
#include <stdint.h>

#define S_DIM 2048
#define B_DIM 2
#define D_DIM 2048
#define H_DIM 16
#define C_DIM 128
#define M_DIM 4096   // S*B rows, row = s*B + b

typedef __bf16 bf16x8 __attribute__((ext_vector_type(8)));
typedef float f32x4 __attribute__((ext_vector_type(4)));
typedef unsigned short u16x8 __attribute__((ext_vector_type(8)));

__device__ __forceinline__ float bf2f(unsigned short u) {
    union { unsigned int i; float f; } c; c.i = ((unsigned int)u) << 16; return c.f;
}
__device__ __forceinline__ unsigned short f2bf(float f) {
    union { float f; unsigned int i; } c; c.f = f;
    unsigned int r = c.i + 0x7FFFu + ((c.i >> 16) & 1u);  // RTN-even
    return (unsigned short)(r >> 16);
}

// ---------------- cos/sin tables for RoPE ----------------
__global__ void rope_tables_k(const float* __restrict__ freqs,
                              float* __restrict__ ctab, float* __restrict__ stab, int n) {
    int i = blockIdx.x * blockDim.x + threadIdx.x;
    if (i < n) { float f = freqs[i]; ctab[i] = cosf(f); stab[i] = sinf(f); }
}

// ---------------- fp32 -> bf16 cast (vectorized) ----------------
__global__ void cast_bf16_k(const float* __restrict__ in, unsigned short* __restrict__ out, int n4) {
    int stride = gridDim.x * blockDim.x;
    for (int i = blockIdx.x * blockDim.x + threadIdx.x; i < n4; i += stride) {
        float4 v = reinterpret_cast<const float4*>(in)[i];
        ushort4 o;
        o.x = f2bf(v.x); o.y = f2bf(v.y); o.z = f2bf(v.z); o.w = f2bf(v.w);
        reinterpret_cast<ushort4*>(out)[i] = o;
    }
}

// ---------------- GEMM: C[M,N] = A[M,K] * B[N,K]^T  (both bf16, K-contiguous) ----
// 128x128 tile, BK=32, 4 waves (2x2), 4x4 16x16x32 MFMA fragments per wave.
// global_load_lds width=16 staging, linear LDS (m97 structure).
template <typename OutT>
__global__ __launch_bounds__(256) void gemm_bt_k(
    const unsigned short* __restrict__ A,
    const unsigned short* __restrict__ Bm,
    OutT* __restrict__ C,
    int M, int N, int K)
{
    constexpr int BK = 32;
    __shared__ __align__(16) unsigned short ldsA[128 * BK];
    __shared__ __align__(16) unsigned short ldsB[128 * BK];

    const int tid  = threadIdx.x;
    const int wave = tid >> 6;
    const int lane = tid & 63;
    const int brow = blockIdx.x * 128;
    const int bcol = blockIdx.y * 128;
    const int wr = (wave >> 1) * 64;   // wave row offset in tile
    const int wc = (wave & 1) * 64;    // wave col offset in tile

    f32x4 acc[4][4] = {};

    const int kc = (lane & 3) * 8;     // k element offset for staging lane

    for (int kt = 0; kt < K; kt += BK) {
        __syncthreads();
        #pragma unroll
        for (int j = 0; j < 2; ++j) {
            const int i = wave * 2 + j;                 // 8 wave-instructions, 1KB each
            const int r = i * 16 + (lane >> 2);         // tile row staged by this lane
            __builtin_amdgcn_global_load_lds(
                (const __attribute__((address_space(1))) void*)(A + (size_t)(brow + r) * K + kt + kc),
                (__attribute__((address_space(3))) void*)(ldsA + i * 512),
                16, 0, 0);
            __builtin_amdgcn_global_load_lds(
                (const __attribute__((address_space(1))) void*)(Bm + (size_t)(bcol + r) * K + kt + kc),
                (__attribute__((address_space(3))) void*)(ldsB + i * 512),
                16, 0, 0);
        }
        __syncthreads();

        const int ro = lane & 15;
        const int ko = (lane >> 4) * 8;
        bf16x8 af[4], bfr[4];
        #pragma unroll
        for (int mi = 0; mi < 4; ++mi)
            af[mi] = *reinterpret_cast<const bf16x8*>(ldsA + (wr + mi * 16 + ro) * BK + ko);
        #pragma unroll
        for (int ni = 0; ni < 4; ++ni)
            bfr[ni] = *reinterpret_cast<const bf16x8*>(ldsB + (wc + ni * 16 + ro) * BK + ko);
        #pragma unroll
        for (int mi = 0; mi < 4; ++mi)
            #pragma unroll
            for (int ni = 0; ni < 4; ++ni)
                acc[mi][ni] = __builtin_amdgcn_mfma_f32_16x16x32_bf16(af[mi], bfr[ni], acc[mi][ni], 0, 0, 0);
    }

    // epilogue: C/D layout col=lane&15, row=(lane>>4)*4+reg  (m89-verified)
    const int ro = lane & 15;
    const int rg = (lane >> 4) * 4;
    #pragma unroll
    for (int mi = 0; mi < 4; ++mi) {
        #pragma unroll
        for (int r = 0; r < 4; ++r) {
            const int row = brow + wr + mi * 16 + rg + r;
            const size_t base = (size_t)row * N + bcol + wc;
            #pragma unroll
            for (int ni = 0; ni < 4; ++ni) {
                float v = acc[mi][ni][r];
                if constexpr (sizeof(OutT) == 2) C[base + ni * 16 + ro] = f2bf(v);
                else                             C[base + ni * 16 + ro] = v;
            }
        }
    }
}

// ---------------- per-head RMSNorm + RoPE on Q/K, relayout to [b*H+h][s][c] ----
// one wave per (m=s*B+b, h); 2 channels per lane (c = 2*lane, 2*lane+1)
__global__ __launch_bounds__(256) void qk_post_k(
    const unsigned short* __restrict__ raw,   // [M][ld], head h at col h*C
    int ld,
    const float* __restrict__ wscale,         // [C]
    const float* __restrict__ ctab, const float* __restrict__ stab, // [S][C]
    unsigned short* __restrict__ outp)        // [B*H][S][C]
{
    const int gw = blockIdx.x * 4 + (threadIdx.x >> 6);
    const int lane = threadIdx.x & 63;
    const int m = gw >> 4;          // row in [0, M)
    const int h = gw & 15;
    const int s = m >> 1, b = m & 1;
    const int c0 = lane * 2;

    const unsigned short* src = raw + (size_t)m * ld + h * C_DIM + c0;
    unsigned int packed = *reinterpret_cast<const unsigned int*>(src);
    float x0 = bf2f((unsigned short)(packed & 0xFFFF));
    float x1 = bf2f((unsigned short)(packed >> 16));

    float ss = x0 * x0 + x1 * x1;
    #pragma unroll
    for (int off = 32; off; off >>= 1) ss += __shfl_xor(ss, off);
    const float rs = rsqrtf(ss * (1.0f / C_DIM) + 1e-6f);

    float n0 = x0 * rs * wscale[c0];
    float n1 = x1 * rs * wscale[c0 + 1];
    // RoPE: partner channel c +/- 64 lives in lane^32
    float p0 = __shfl_xor(n0, 32);
    float p1 = __shfl_xor(n1, 32);
    const float sgn = (lane < 32) ? -1.0f : 1.0f;
    const float* cp = ctab + (size_t)s * C_DIM + c0;
    const float* sp = stab + (size_t)s * C_DIM + c0;
    float o0 = n0 * cp[0] + sgn * p0 * sp[0];
    float o1 = n1 * cp[1] + sgn * p1 * sp[1];

    unsigned int opk = (unsigned int)f2bf(o0) | ((unsigned int)f2bf(o1) << 16);
    *reinterpret_cast<unsigned int*>(
        outp + ((size_t)(b * H_DIM + h) * S_DIM + s) * C_DIM + c0) = opk;
}

// ---------------- V relayout+transpose: raw [M][ld] (V at col 2*D) -> Vt [b*H+h][C][S] ----
__global__ __launch_bounds__(256) void v_transpose_k(
    const unsigned short* __restrict__ raw, int ld, int colbase,
    unsigned short* __restrict__ Vt)
{
    __shared__ __align__(16) unsigned short tile[64][136];  // +8 pad
    const int bh = blockIdx.y;
    const int b = bh >> 4, h = bh & 15;
    const int sbase = blockIdx.x * 64;
    const int t = threadIdx.x;

    {   // load 64 s-rows x 128 c, coalesced 16B
        const int s = t >> 2, cq = (t & 3) * 32;
        const unsigned short* src = raw + (size_t)((sbase + s) * B_DIM + b) * ld + colbase + h * C_DIM + cq;
        #pragma unroll
        for (int j = 0; j < 4; ++j) {
            u16x8 v = *reinterpret_cast<const u16x8*>(src + j * 8);
            *reinterpret_cast<u16x8*>(&tile[s][cq + j * 8]) = v;
        }
    }
    __syncthreads();
    {   // write 128 c-rows x 64 s, coalesced 16B
        const int c = t >> 1, sh = (t & 1) * 32;
        unsigned short* dst = Vt + ((size_t)bh * C_DIM + c) * S_DIM + sbase + sh;
        #pragma unroll
        for (int j = 0; j < 32; j += 8) {
            u16x8 o;
            #pragma unroll
            for (int e = 0; e < 8; ++e) o[e] = tile[sh + j + e][c];
            *reinterpret_cast<u16x8*>(dst + j) = o;
        }
    }
}

// ---------------- flash attention v2: cooperative LDS-staged, double-buffered ----
// grid (S/128, B*H); 8 waves/block, each wave owns 16 q-rows; KVBLK=64 per step.
// K tile [64][128] and V tile [128][64] staged via global_load_lds w=16 with
// XOR chunk swizzle (pre-swizzled global source, swizzled LDS read).
__global__ __launch_bounds__(512) void attn_k(
    const unsigned short* __restrict__ Qb,
    const unsigned short* __restrict__ Kb,
    const unsigned short* __restrict__ Vt,
    unsigned short* __restrict__ Ao)          // [M][D], row = s*B+b, col = h*C+c
{
    __shared__ __align__(16) unsigned short ldsK[2][64 * 128];   // 32 KiB
    __shared__ __align__(16) unsigned short ldsV[2][128 * 64];   // 32 KiB
    __shared__ __align__(16) unsigned short plds[8][16][72];     // 18 KiB, per-wave P

    const int bh = blockIdx.y;
    const int wave = threadIdx.x >> 6;
    const int lane = threadIdx.x & 63;
    const int qbase = blockIdx.x * 128 + wave * 16;
    const int g  = lane >> 4;       // k-slot group 0..3
    const int ro = lane & 15;
    const int ko = g * 8;
    const int rg = g * 4;

    const unsigned short* Q  = Qb + (size_t)bh * S_DIM * C_DIM;
    const unsigned short* Km = Kb + (size_t)bh * S_DIM * C_DIM;
    const unsigned short* V  = Vt + (size_t)bh * C_DIM * S_DIM;

    bf16x8 qf[4];
    #pragma unroll
    for (int kf = 0; kf < 4; ++kf)
        qf[kf] = *reinterpret_cast<const bf16x8*>(Q + (size_t)(qbase + ro) * C_DIM + kf * 32 + ko);

    // stage K[kb..kb+64)x128 and V[0..128)x[kb..kb+64) into buffer bufi.
    // LDS dest is linear (wave-uniform base + lane*16); global source is
    // inverse-XOR-swizzled so that LDS chunk x of row r holds global chunk
    // (x&8)|((x^r)&7)  (K: 16 chunks/row)  /  (x^r)&7  (V: 8 chunks/row).
    auto stage = [&](int bufi, int kb) {
        #pragma unroll
        for (int j = 0; j < 2; ++j) {
            const int idx = (wave * 2 + j) * 64 + lane;
            {   // K tile: row = idx>>4 (64 rows), chunk = idx&15 (256B rows)
                const int row = idx >> 4, ch = idx & 15;
                const int sch = (ch & 8) | ((ch ^ row) & 7);
                __builtin_amdgcn_global_load_lds(
                    (const __attribute__((address_space(1))) void*)(
                        Km + (size_t)(kb + row) * C_DIM + sch * 8),
                    (__attribute__((address_space(3))) void*)(
                        &ldsK[bufi][(wave * 2 + j) * 512]),
                    16, 0, 0);
            }
            {   // V tile: row = idx>>3 (128 rows), chunk = idx&7 (128B rows)
                const int row = idx >> 3, ch = idx & 7;
                const int sch = (ch ^ row) & 7;
                __builtin_amdgcn_global_load_lds(
                    (const __attribute__((address_space(1))) void*)(
                        V + (size_t)row * S_DIM + kb + sch * 8),
                    (__attribute__((address_space(3))) void*)(
                        &ldsV[bufi][(wave * 2 + j) * 512]),
                    16, 0, 0);
            }
        }
    };

    f32x4 of[8] = {};
    float mrow[4] = {-1e30f, -1e30f, -1e30f, -1e30f};
    float lrow[4] = {0.f, 0.f, 0.f, 0.f};
    const float inv_scale = 0.08838834764831845f;  // 1/sqrt(128)

    stage(0, 0);
    asm volatile("s_waitcnt vmcnt(0)" ::: "memory");
    __syncthreads();

    int cur = 0;
    for (int kb = 0; kb < S_DIM; kb += 64) {
        if (kb + 64 < S_DIM) stage(cur ^ 1, kb + 64);

        // ---- QK^T: 64 k-cols as 4 n-fragments ----
        f32x4 s4[4] = {};
        #pragma unroll
        for (int nc = 0; nc < 4; ++nc) {
            const int r_loc = nc * 16 + ro;
            #pragma unroll
            for (int kf = 0; kf < 4; ++kf) {
                const int c = kf * 4 + g;
                const int sch = (c & 8) | ((c ^ r_loc) & 7);
                bf16x8 kfr = *reinterpret_cast<const bf16x8*>(
                    &ldsK[cur][r_loc * 128 + sch * 8]);
                s4[nc] = __builtin_amdgcn_mfma_f32_16x16x32_bf16(qf[kf], kfr, s4[nc], 0, 0, 0);
            }
        }

        // ---- online softmax over the 64 columns ----
        #pragma unroll
        for (int nc = 0; nc < 4; ++nc)
            #pragma unroll
            for (int r = 0; r < 4; ++r) s4[nc][r] *= inv_scale;

        float mx[4];
        #pragma unroll
        for (int r = 0; r < 4; ++r)
            mx[r] = fmaxf(fmaxf(s4[0][r], s4[1][r]), fmaxf(s4[2][r], s4[3][r]));
        #pragma unroll
        for (int off = 1; off < 16; off <<= 1)
            #pragma unroll
            for (int r = 0; r < 4; ++r) mx[r] = fmaxf(mx[r], __shfl_xor(mx[r], off));

        float resc[4], ladd[4];
        #pragma unroll
        for (int r = 0; r < 4; ++r) {
            float mnew = fmaxf(mrow[r], mx[r]);
            resc[r] = __expf(mrow[r] - mnew);
            mrow[r] = mnew;
            float p0 = __expf(s4[0][r] - mnew);
            float p1 = __expf(s4[1][r] - mnew);
            float p2 = __expf(s4[2][r] - mnew);
            float p3 = __expf(s4[3][r] - mnew);
            s4[0][r] = p0; s4[1][r] = p1; s4[2][r] = p2; s4[3][r] = p3;
            ladd[r] = (p0 + p1) + (p2 + p3);
        }
        #pragma unroll
        for (int off = 1; off < 16; off <<= 1)
            #pragma unroll
            for (int r = 0; r < 4; ++r) ladd[r] += __shfl_xor(ladd[r], off);
        #pragma unroll
        for (int r = 0; r < 4; ++r) lrow[r] = lrow[r] * resc[r] + ladd[r];
        #pragma unroll
        for (int nf = 0; nf < 8; ++nf)
            #pragma unroll
            for (int r = 0; r < 4; ++r) of[nf][r] *= resc[r];

        // ---- P (C-frag layout) -> per-wave LDS -> A-frag layout ----
        #pragma unroll
        for (int nc = 0; nc < 4; ++nc)
            #pragma unroll
            for (int r = 0; r < 4; ++r)
                plds[wave][rg + r][nc * 16 + ro] = f2bf(s4[nc][r]);
        __asm__ volatile("" ::: "memory");

        // ---- PV: 2 k-slices of 32 ----
        #pragma unroll
        for (int ks = 0; ks < 2; ++ks) {
            bf16x8 pa = *reinterpret_cast<const bf16x8*>(&plds[wave][ro][ks * 32 + ko]);
            #pragma unroll
            for (int nf = 0; nf < 8; ++nf) {
                const int vr = nf * 16 + ro;
                const int c = ks * 4 + g;
                const int sch = (c ^ vr) & 7;
                bf16x8 vf = *reinterpret_cast<const bf16x8*>(&ldsV[cur][vr * 64 + sch * 8]);
                of[nf] = __builtin_amdgcn_mfma_f32_16x16x32_bf16(pa, vf, of[nf], 0, 0, 0);
            }
        }

        asm volatile("s_waitcnt vmcnt(0)" ::: "memory");
        __syncthreads();
        cur ^= 1;
    }

    const int b = bh >> 4, h = bh & 15;
    float inv_l[4];
    #pragma unroll
    for (int r = 0; r < 4; ++r) inv_l[r] = 1.0f / lrow[r];
    #pragma unroll
    for (int r = 0; r < 4; ++r) {
        const int srow = qbase + rg + r;
        unsigned short* dst = Ao + (size_t)(srow * B_DIM + b) * D_DIM + h * C_DIM;
        #pragma unroll
        for (int nf = 0; nf < 8; ++nf)
            dst[nf * 16 + ro] = f2bf(of[nf][r] * inv_l[r]);
    }
}

extern "C" void kernel_launch(void* const* d_in, const int* in_sizes, int n_in,
                              void* d_out, int out_size, void* d_ws, size_t ws_size,
                              hipStream_t stream) {
    const float* x       = (const float*)d_in[0];
    const float* rope    = (const float*)d_in[1];
    const float* Wq      = (const float*)d_in[2];
    const float* Wk      = (const float*)d_in[3];
    const float* Wv      = (const float*)d_in[4];
    const float* Wo      = (const float*)d_in[5];
    const float* q_scale = (const float*)d_in[6];
    const float* k_scale = (const float*)d_in[7];
    float* out = (float*)d_out;

    char* w = (char*)d_ws;
    size_t off = 0;
    auto alloc = [&](size_t bytes) {
        char* p = w + off; off += (bytes + 255) & ~(size_t)255; return p;
    };
    unsigned short* xb   = (unsigned short*)alloc((size_t)M_DIM * D_DIM * 2);  // 16 MiB
    unsigned short* Wqb  = (unsigned short*)alloc((size_t)D_DIM * D_DIM * 2);  // contiguous
    unsigned short* Wkb  = (unsigned short*)alloc((size_t)D_DIM * D_DIM * 2);  //   Wq|Wk|Wv
    unsigned short* Wvb  = (unsigned short*)alloc((size_t)D_DIM * D_DIM * 2);
    unsigned short* Wob  = (unsigned short*)alloc((size_t)D_DIM * D_DIM * 2);
    unsigned short* rawQKV = (unsigned short*)alloc((size_t)M_DIM * 3 * D_DIM * 2); // [M][6144]
    unsigned short* Qb   = (unsigned short*)alloc((size_t)M_DIM * D_DIM * 2);
    unsigned short* Kb   = (unsigned short*)alloc((size_t)M_DIM * D_DIM * 2);
    unsigned short* Vt   = (unsigned short*)alloc((size_t)M_DIM * D_DIM * 2);
    float* ctab = (float*)alloc((size_t)S_DIM * C_DIM * 4);
    float* stab = (float*)alloc((size_t)S_DIM * C_DIM * 4);
    unsigned short* Ao = rawQKV;  // reuse (rawQKV dead before attention writes)
    (void)Wkb; (void)Wvb; (void)ws_size; (void)in_sizes; (void)n_in; (void)out_size;

    const int NQKV = 3 * D_DIM;  // 6144

    rope_tables_k<<<(S_DIM * C_DIM + 255) / 256, 256, 0, stream>>>(rope, ctab, stab, S_DIM * C_DIM);
    cast_bf16_k<<<1024, 256, 0, stream>>>(x,  xb,  M_DIM * D_DIM / 4);
    cast_bf16_k<<<1024, 256, 0, stream>>>(Wq, Wqb, D_DIM * D_DIM / 4);
    cast_bf16_k<<<1024, 256, 0, stream>>>(Wk, Wkb, D_DIM * D_DIM / 4);
    cast_bf16_k<<<1024, 256, 0, stream>>>(Wv, Wvb, D_DIM * D_DIM / 4);
    cast_bf16_k<<<1024, 256, 0, stream>>>(Wo, Wob, D_DIM * D_DIM / 4);

    // fused QKV projection: [4096,2048] x [6144,2048]^T
    gemm_bt_k<unsigned short><<<dim3(M_DIM / 128, NQKV / 128), 256, 0, stream>>>(
        xb, Wqb, rawQKV, M_DIM, NQKV, D_DIM);

    qk_post_k<<<M_DIM * H_DIM / 4, 256, 0, stream>>>(rawQKV,              NQKV, q_scale, ctab, stab, Qb);
    qk_post_k<<<M_DIM * H_DIM / 4, 256, 0, stream>>>(rawQKV + D_DIM,      NQKV, k_scale, ctab, stab, Kb);
    v_transpose_k<<<dim3(S_DIM / 64, B_DIM * H_DIM), 256, 0, stream>>>(rawQKV, NQKV, 2 * D_DIM, Vt);

    attn_k<<<dim3(S_DIM / 128, B_DIM * H_DIM), 512, 0, stream>>>(Qb, Kb, Vt, Ao);

    // out projection: [4096,2048] x [2048,2048]^T -> fp32 d_out
    gemm_bt_k<float><<<dim3(M_DIM / 128, D_DIM / 128), 256, 0, stream>>>(
        Ao, Wob, out, M_DIM, D_DIM, D_DIM);
}

// Round 3
// 387.315 us; speedup vs baseline: 2.3716x; 1.0675x over previous
//
#include <hip/hip_runtime.h>
#include <stdint.h>

#define S_DIM 2048
#define B_DIM 2
#define D_DIM 2048
#define H_DIM 16
#define C_DIM 128
#define M_DIM 4096   // S*B rows, row = s*B + b

typedef __bf16 bf16x8 __attribute__((ext_vector_type(8)));
typedef float f32x4 __attribute__((ext_vector_type(4)));
typedef unsigned short u16x8 __attribute__((ext_vector_type(8)));

__device__ __forceinline__ float bf2f(unsigned short u) {
    union { unsigned int i; float f; } c; c.i = ((unsigned int)u) << 16; return c.f;
}
__device__ __forceinline__ unsigned short f2bf(float f) {
    union { float f; unsigned int i; } c; c.f = f;
    unsigned int r = c.i + 0x7FFFu + ((c.i >> 16) & 1u);  // RTN-even
    return (unsigned short)(r >> 16);
}

// ---------------- cos/sin tables for RoPE ----------------
__global__ void rope_tables_k(const float* __restrict__ freqs,
                              float* __restrict__ ctab, float* __restrict__ stab, int n) {
    int i = blockIdx.x * blockDim.x + threadIdx.x;
    if (i < n) { float f = freqs[i]; ctab[i] = cosf(f); stab[i] = sinf(f); }
}

// ---------------- fp32 -> bf16 cast (vectorized) ----------------
__global__ void cast_bf16_k(const float* __restrict__ in, unsigned short* __restrict__ out, int n4) {
    int stride = gridDim.x * blockDim.x;
    for (int i = blockIdx.x * blockDim.x + threadIdx.x; i < n4; i += stride) {
        float4 v = reinterpret_cast<const float4*>(in)[i];
        ushort4 o;
        o.x = f2bf(v.x); o.y = f2bf(v.y); o.z = f2bf(v.z); o.w = f2bf(v.w);
        reinterpret_cast<ushort4*>(out)[i] = o;
    }
}

// ---------------- GEMM: C[M,N] = A[M,K] * B[N,K]^T  (both bf16, K-contiguous) ----
// 128x128 tile, BK=32, 4 waves (2x2), 4x4 16x16x32 MFMA fragments per wave.
// global_load_lds width=16 staging, linear LDS (m97 structure).
template <typename OutT>
__global__ __launch_bounds__(256) void gemm_bt_k(
    const unsigned short* __restrict__ A,
    const unsigned short* __restrict__ Bm,
    OutT* __restrict__ C,
    int M, int N, int K)
{
    constexpr int BK = 32;
    __shared__ __align__(16) unsigned short ldsA[128 * BK];
    __shared__ __align__(16) unsigned short ldsB[128 * BK];

    const int tid  = threadIdx.x;
    const int wave = tid >> 6;
    const int lane = tid & 63;
    const int brow = blockIdx.x * 128;
    const int bcol = blockIdx.y * 128;
    const int wr = (wave >> 1) * 64;   // wave row offset in tile
    const int wc = (wave & 1) * 64;    // wave col offset in tile

    f32x4 acc[4][4] = {};

    const int kc = (lane & 3) * 8;     // k element offset for staging lane

    for (int kt = 0; kt < K; kt += BK) {
        __syncthreads();
        #pragma unroll
        for (int j = 0; j < 2; ++j) {
            const int i = wave * 2 + j;                 // 8 wave-instructions, 1KB each
            const int r = i * 16 + (lane >> 2);         // tile row staged by this lane
            __builtin_amdgcn_global_load_lds(
                (const __attribute__((address_space(1))) void*)(A + (size_t)(brow + r) * K + kt + kc),
                (__attribute__((address_space(3))) void*)(ldsA + i * 512),
                16, 0, 0);
            __builtin_amdgcn_global_load_lds(
                (const __attribute__((address_space(1))) void*)(Bm + (size_t)(bcol + r) * K + kt + kc),
                (__attribute__((address_space(3))) void*)(ldsB + i * 512),
                16, 0, 0);
        }
        __syncthreads();

        const int ro = lane & 15;
        const int ko = (lane >> 4) * 8;
        bf16x8 af[4], bfr[4];
        #pragma unroll
        for (int mi = 0; mi < 4; ++mi)
            af[mi] = *reinterpret_cast<const bf16x8*>(ldsA + (wr + mi * 16 + ro) * BK + ko);
        #pragma unroll
        for (int ni = 0; ni < 4; ++ni)
            bfr[ni] = *reinterpret_cast<const bf16x8*>(ldsB + (wc + ni * 16 + ro) * BK + ko);
        #pragma unroll
        for (int mi = 0; mi < 4; ++mi)
            #pragma unroll
            for (int ni = 0; ni < 4; ++ni)
                acc[mi][ni] = __builtin_amdgcn_mfma_f32_16x16x32_bf16(af[mi], bfr[ni], acc[mi][ni], 0, 0, 0);
    }

    // epilogue: C/D layout col=lane&15, row=(lane>>4)*4+reg  (m89-verified)
    const int ro = lane & 15;
    const int rg = (lane >> 4) * 4;
    #pragma unroll
    for (int mi = 0; mi < 4; ++mi) {
        #pragma unroll
        for (int r = 0; r < 4; ++r) {
            const int row = brow + wr + mi * 16 + rg + r;
            const size_t base = (size_t)row * N + bcol + wc;
            #pragma unroll
            for (int ni = 0; ni < 4; ++ni) {
                float v = acc[mi][ni][r];
                if constexpr (sizeof(OutT) == 2) C[base + ni * 16 + ro] = f2bf(v);
                else                             C[base + ni * 16 + ro] = v;
            }
        }
    }
}

// ---------------- per-head RMSNorm + RoPE on Q/K, relayout to [b*H+h][s][c] ----
// one wave per (m=s*B+b, h); 2 channels per lane (c = 2*lane, 2*lane+1)
__global__ __launch_bounds__(256) void qk_post_k(
    const unsigned short* __restrict__ raw,   // [M][ld], head h at col h*C
    int ld,
    const float* __restrict__ wscale,         // [C]
    const float* __restrict__ ctab, const float* __restrict__ stab, // [S][C]
    unsigned short* __restrict__ outp)        // [B*H][S][C]
{
    const int gw = blockIdx.x * 4 + (threadIdx.x >> 6);
    const int lane = threadIdx.x & 63;
    const int m = gw >> 4;          // row in [0, M)
    const int h = gw & 15;
    const int s = m >> 1, b = m & 1;
    const int c0 = lane * 2;

    const unsigned short* src = raw + (size_t)m * ld + h * C_DIM + c0;
    unsigned int packed = *reinterpret_cast<const unsigned int*>(src);
    float x0 = bf2f((unsigned short)(packed & 0xFFFF));
    float x1 = bf2f((unsigned short)(packed >> 16));

    float ss = x0 * x0 + x1 * x1;
    #pragma unroll
    for (int off = 32; off; off >>= 1) ss += __shfl_xor(ss, off);
    const float rs = rsqrtf(ss * (1.0f / C_DIM) + 1e-6f);

    float n0 = x0 * rs * wscale[c0];
    float n1 = x1 * rs * wscale[c0 + 1];
    // RoPE: partner channel c +/- 64 lives in lane^32
    float p0 = __shfl_xor(n0, 32);
    float p1 = __shfl_xor(n1, 32);
    const float sgn = (lane < 32) ? -1.0f : 1.0f;
    const float* cp = ctab + (size_t)s * C_DIM + c0;
    const float* sp = stab + (size_t)s * C_DIM + c0;
    float o0 = n0 * cp[0] + sgn * p0 * sp[0];
    float o1 = n1 * cp[1] + sgn * p1 * sp[1];

    unsigned int opk = (unsigned int)f2bf(o0) | ((unsigned int)f2bf(o1) << 16);
    *reinterpret_cast<unsigned int*>(
        outp + ((size_t)(b * H_DIM + h) * S_DIM + s) * C_DIM + c0) = opk;
}

// ---------------- V relayout+transpose: raw [M][ld] (V at col 2*D) -> Vt [b*H+h][C][S] ----
__global__ __launch_bounds__(256) void v_transpose_k(
    const unsigned short* __restrict__ raw, int ld, int colbase,
    unsigned short* __restrict__ Vt)
{
    __shared__ __align__(16) unsigned short tile[64][136];  // +8 pad
    const int bh = blockIdx.y;
    const int b = bh >> 4, h = bh & 15;
    const int sbase = blockIdx.x * 64;
    const int t = threadIdx.x;

    {   // load 64 s-rows x 128 c, coalesced 16B
        const int s = t >> 2, cq = (t & 3) * 32;
        const unsigned short* src = raw + (size_t)((sbase + s) * B_DIM + b) * ld + colbase + h * C_DIM + cq;
        #pragma unroll
        for (int j = 0; j < 4; ++j) {
            u16x8 v = *reinterpret_cast<const u16x8*>(src + j * 8);
            *reinterpret_cast<u16x8*>(&tile[s][cq + j * 8]) = v;
        }
    }
    __syncthreads();
    {   // write 128 c-rows x 64 s, coalesced 16B
        const int c = t >> 1, sh = (t & 1) * 32;
        unsigned short* dst = Vt + ((size_t)bh * C_DIM + c) * S_DIM + sbase + sh;
        #pragma unroll
        for (int j = 0; j < 32; j += 8) {
            u16x8 o;
            #pragma unroll
            for (int e = 0; e < 8; ++e) o[e] = tile[sh + j + e][c];
            *reinterpret_cast<u16x8*>(dst + j) = o;
        }
    }
}

// ---------------- flash attention v3: cooperative LDS-staged, double-buffered ----
// grid (S/128, B*H); 8 waves/block, each wave owns 16 q-rows; KVBLK=64 per step.
// LDS = 80KB exactly -> 2 blocks/CU (cross-block latency hiding).
// K tile [64][128], V tile [128][64], P tile [16][64] all XOR-chunk-swizzled.
__global__ __launch_bounds__(512, 4) void attn_k(
    const unsigned short* __restrict__ Qb,
    const unsigned short* __restrict__ Kb,
    const unsigned short* __restrict__ Vt,
    unsigned short* __restrict__ Ao)          // [M][D], row = s*B+b, col = h*C+c
{
    __shared__ __align__(16) unsigned short ldsK[2][64 * 128];   // 32 KiB
    __shared__ __align__(16) unsigned short ldsV[2][128 * 64];   // 32 KiB
    __shared__ __align__(16) unsigned short plds[8][16 * 64];    // 16 KiB, per-wave P (swizzled)

    const int bh = blockIdx.y;
    const int wave = threadIdx.x >> 6;
    const int lane = threadIdx.x & 63;
    const int qbase = blockIdx.x * 128 + wave * 16;
    const int g  = lane >> 4;       // k-slot group 0..3
    const int ro = lane & 15;
    const int ko = g * 8;
    const int rg = g * 4;

    const unsigned short* Q  = Qb + (size_t)bh * S_DIM * C_DIM;
    const unsigned short* Km = Kb + (size_t)bh * S_DIM * C_DIM;
    const unsigned short* V  = Vt + (size_t)bh * C_DIM * S_DIM;
    unsigned short* pw = &plds[wave][0];

    bf16x8 qf[4];
    #pragma unroll
    for (int kf = 0; kf < 4; ++kf)
        qf[kf] = *reinterpret_cast<const bf16x8*>(Q + (size_t)(qbase + ro) * C_DIM + kf * 32 + ko);

    // stage K[kb..kb+64)x128 and V[0..128)x[kb..kb+64) into buffer bufi.
    // LDS dest is linear (wave-uniform base + lane*16); global source is
    // inverse-XOR-swizzled so that LDS chunk x of row r holds global chunk
    // (x&8)|((x^r)&7)  (K: 16 chunks/row)  /  (x^r)&7  (V: 8 chunks/row).
    auto stage = [&](int bufi, int kb) {
        #pragma unroll
        for (int j = 0; j < 2; ++j) {
            const int idx = (wave * 2 + j) * 64 + lane;
            {   // K tile: row = idx>>4 (64 rows), chunk = idx&15 (256B rows)
                const int row = idx >> 4, ch = idx & 15;
                const int sch = (ch & 8) | ((ch ^ row) & 7);
                __builtin_amdgcn_global_load_lds(
                    (const __attribute__((address_space(1))) void*)(
                        Km + (size_t)(kb + row) * C_DIM + sch * 8),
                    (__attribute__((address_space(3))) void*)(
                        &ldsK[bufi][(wave * 2 + j) * 512]),
                    16, 0, 0);
            }
            {   // V tile: row = idx>>3 (128 rows), chunk = idx&7 (128B rows)
                const int row = idx >> 3, ch = idx & 7;
                const int sch = (ch ^ row) & 7;
                __builtin_amdgcn_global_load_lds(
                    (const __attribute__((address_space(1))) void*)(
                        V + (size_t)row * S_DIM + kb + sch * 8),
                    (__attribute__((address_space(3))) void*)(
                        &ldsV[bufi][(wave * 2 + j) * 512]),
                    16, 0, 0);
            }
        }
    };

    f32x4 of[8] = {};
    float mrow[4] = {-1e30f, -1e30f, -1e30f, -1e30f};
    float lrow[4] = {0.f, 0.f, 0.f, 0.f};
    const float inv_scale = 0.08838834764831845f;  // 1/sqrt(128)

    stage(0, 0);
    asm volatile("s_waitcnt vmcnt(0)" ::: "memory");
    __syncthreads();

    int cur = 0;
    for (int kb = 0; kb < S_DIM; kb += 64) {
        if (kb + 64 < S_DIM) stage(cur ^ 1, kb + 64);

        // ---- QK^T: 64 k-cols as 4 n-fragments ----
        f32x4 s4[4] = {};
        __builtin_amdgcn_s_setprio(1);
        #pragma unroll
        for (int nc = 0; nc < 4; ++nc) {
            const int r_loc = nc * 16 + ro;
            #pragma unroll
            for (int kf = 0; kf < 4; ++kf) {
                const int c = kf * 4 + g;
                const int sch = (c & 8) | ((c ^ r_loc) & 7);
                bf16x8 kfr = *reinterpret_cast<const bf16x8*>(
                    &ldsK[cur][r_loc * 128 + sch * 8]);
                s4[nc] = __builtin_amdgcn_mfma_f32_16x16x32_bf16(qf[kf], kfr, s4[nc], 0, 0, 0);
            }
        }
        __builtin_amdgcn_s_setprio(0);

        // ---- online softmax over the 64 columns ----
        #pragma unroll
        for (int nc = 0; nc < 4; ++nc)
            #pragma unroll
            for (int r = 0; r < 4; ++r) s4[nc][r] *= inv_scale;

        float mx[4];
        #pragma unroll
        for (int r = 0; r < 4; ++r)
            mx[r] = fmaxf(fmaxf(s4[0][r], s4[1][r]), fmaxf(s4[2][r], s4[3][r]));
        #pragma unroll
        for (int off = 1; off < 16; off <<= 1)
            #pragma unroll
            for (int r = 0; r < 4; ++r) mx[r] = fmaxf(mx[r], __shfl_xor(mx[r], off));

        // T13 defer-max: only rescale when the running max grows by >8
        float mg = 0.f;
        #pragma unroll
        for (int r = 0; r < 4; ++r) mg = fmaxf(mg, mx[r] - mrow[r]);
        if (__any(mg > 8.0f)) {
            float resc[4];
            #pragma unroll
            for (int r = 0; r < 4; ++r) {
                float mnew = fmaxf(mrow[r], mx[r]);
                resc[r] = __expf(mrow[r] - mnew);
                mrow[r] = mnew;
                lrow[r] *= resc[r];
            }
            #pragma unroll
            for (int nf = 0; nf < 8; ++nf)
                #pragma unroll
                for (int r = 0; r < 4; ++r) of[nf][r] *= resc[r];
        }

        float ladd[4];
        #pragma unroll
        for (int r = 0; r < 4; ++r) {
            float p0 = __expf(s4[0][r] - mrow[r]);
            float p1 = __expf(s4[1][r] - mrow[r]);
            float p2 = __expf(s4[2][r] - mrow[r]);
            float p3 = __expf(s4[3][r] - mrow[r]);
            s4[0][r] = p0; s4[1][r] = p1; s4[2][r] = p2; s4[3][r] = p3;
            ladd[r] = (p0 + p1) + (p2 + p3);
        }
        #pragma unroll
        for (int off = 1; off < 16; off <<= 1)
            #pragma unroll
            for (int r = 0; r < 4; ++r) ladd[r] += __shfl_xor(ladd[r], off);
        #pragma unroll
        for (int r = 0; r < 4; ++r) lrow[r] += ladd[r];

        // ---- P (C-frag layout) -> per-wave swizzled LDS -> A-frag layout ----
        // write: elem (q = rg+r, k = nc*16+ro) at q*64 + ((k>>3)^(q&7))*8 + (k&7)
        #pragma unroll
        for (int nc = 0; nc < 4; ++nc)
            #pragma unroll
            for (int r = 0; r < 4; ++r) {
                const int q = rg + r;
                const int k = nc * 16 + ro;
                pw[q * 64 + (((k >> 3) ^ (q & 7)) << 3) + (k & 7)] = f2bf(s4[nc][r]);
            }
        __asm__ volatile("" ::: "memory");

        // ---- PV: 2 k-slices of 32 ----
        __builtin_amdgcn_s_setprio(1);
        #pragma unroll
        for (int ks = 0; ks < 2; ++ks) {
            const int psch = (ks * 4 + g) ^ (ro & 7);
            bf16x8 pa = *reinterpret_cast<const bf16x8*>(&pw[ro * 64 + psch * 8]);
            #pragma unroll
            for (int nf = 0; nf < 8; ++nf) {
                const int vr = nf * 16 + ro;
                const int c = ks * 4 + g;
                const int sch = (c ^ vr) & 7;
                bf16x8 vf = *reinterpret_cast<const bf16x8*>(&ldsV[cur][vr * 64 + sch * 8]);
                of[nf] = __builtin_amdgcn_mfma_f32_16x16x32_bf16(pa, vf, of[nf], 0, 0, 0);
            }
        }
        __builtin_amdgcn_s_setprio(0);

        asm volatile("s_waitcnt vmcnt(0)" ::: "memory");
        __syncthreads();
        cur ^= 1;
    }

    const int b = bh >> 4, h = bh & 15;
    float inv_l[4];
    #pragma unroll
    for (int r = 0; r < 4; ++r) inv_l[r] = 1.0f / lrow[r];
    #pragma unroll
    for (int r = 0; r < 4; ++r) {
        const int srow = qbase + rg + r;
        unsigned short* dst = Ao + (size_t)(srow * B_DIM + b) * D_DIM + h * C_DIM;
        #pragma unroll
        for (int nf = 0; nf < 8; ++nf)
            dst[nf * 16 + ro] = f2bf(of[nf][r] * inv_l[r]);
    }
}

extern "C" void kernel_launch(void* const* d_in, const int* in_sizes, int n_in,
                              void* d_out, int out_size, void* d_ws, size_t ws_size,
                              hipStream_t stream) {
    const float* x       = (const float*)d_in[0];
    const float* rope    = (const float*)d_in[1];
    const float* Wq      = (const float*)d_in[2];
    const float* Wk      = (const float*)d_in[3];
    const float* Wv      = (const float*)d_in[4];
    const float* Wo      = (const float*)d_in[5];
    const float* q_scale = (const float*)d_in[6];
    const float* k_scale = (const float*)d_in[7];
    float* out = (float*)d_out;

    char* w = (char*)d_ws;
    size_t off = 0;
    auto alloc = [&](size_t bytes) {
        char* p = w + off; off += (bytes + 255) & ~(size_t)255; return p;
    };
    unsigned short* xb   = (unsigned short*)alloc((size_t)M_DIM * D_DIM * 2);  // 16 MiB
    unsigned short* Wqb  = (unsigned short*)alloc((size_t)D_DIM * D_DIM * 2);  // contiguous
    unsigned short* Wkb  = (unsigned short*)alloc((size_t)D_DIM * D_DIM * 2);  //   Wq|Wk|Wv
    unsigned short* Wvb  = (unsigned short*)alloc((size_t)D_DIM * D_DIM * 2);
    unsigned short* Wob  = (unsigned short*)alloc((size_t)D_DIM * D_DIM * 2);
    unsigned short* rawQKV = (unsigned short*)alloc((size_t)M_DIM * 3 * D_DIM * 2); // [M][6144]
    unsigned short* Qb   = (unsigned short*)alloc((size_t)M_DIM * D_DIM * 2);
    unsigned short* Kb   = (unsigned short*)alloc((size_t)M_DIM * D_DIM * 2);
    unsigned short* Vt   = (unsigned short*)alloc((size_t)M_DIM * D_DIM * 2);
    float* ctab = (float*)alloc((size_t)S_DIM * C_DIM * 4);
    float* stab = (float*)alloc((size_t)S_DIM * C_DIM * 4);
    unsigned short* Ao = rawQKV;  // reuse (rawQKV dead before attention writes)
    (void)Wkb; (void)Wvb; (void)ws_size; (void)in_sizes; (void)n_in; (void)out_size;

    const int NQKV = 3 * D_DIM;  // 6144

    rope_tables_k<<<(S_DIM * C_DIM + 255) / 256, 256, 0, stream>>>(rope, ctab, stab, S_DIM * C_DIM);
    cast_bf16_k<<<1024, 256, 0, stream>>>(x,  xb,  M_DIM * D_DIM / 4);
    cast_bf16_k<<<1024, 256, 0, stream>>>(Wq, Wqb, D_DIM * D_DIM / 4);
    cast_bf16_k<<<1024, 256, 0, stream>>>(Wk, Wkb, D_DIM * D_DIM / 4);
    cast_bf16_k<<<1024, 256, 0, stream>>>(Wv, Wvb, D_DIM * D_DIM / 4);
    cast_bf16_k<<<1024, 256, 0, stream>>>(Wo, Wob, D_DIM * D_DIM / 4);

    // fused QKV projection: [4096,2048] x [6144,2048]^T
    gemm_bt_k<unsigned short><<<dim3(M_DIM / 128, NQKV / 128), 256, 0, stream>>>(
        xb, Wqb, rawQKV, M_DIM, NQKV, D_DIM);

    qk_post_k<<<M_DIM * H_DIM / 4, 256, 0, stream>>>(rawQKV,              NQKV, q_scale, ctab, stab, Qb);
    qk_post_k<<<M_DIM * H_DIM / 4, 256, 0, stream>>>(rawQKV + D_DIM,      NQKV, k_scale, ctab, stab, Kb);
    v_transpose_k<<<dim3(S_DIM / 64, B_DIM * H_DIM), 256, 0, stream>>>(rawQKV, NQKV, 2 * D_DIM, Vt);

    attn_k<<<dim3(S_DIM / 128, B_DIM * H_DIM), 512, 0, stream>>>(Qb, Kb, Vt, Ao);

    // out projection: [4096,2048] x [2048,2048]^T -> fp32 d_out
    gemm_bt_k<float><<<dim3(M_DIM / 128, D_DIM / 128), 256, 0, stream>>>(
        Ao, Wob, out, M_DIM, D_DIM, D_DIM);
}

// Round 4
// 381.522 us; speedup vs baseline: 2.4076x; 1.0152x over previous
//
#include <hip/hip_runtime.h>
#include <stdint.h>

#define S_DIM 2048
#define B_DIM 2
#define D_DIM 2048
#define H_DIM 16
#define C_DIM 128
#define M_DIM 4096   // S*B rows, row = s*B + b

typedef __bf16 bf16x8 __attribute__((ext_vector_type(8)));
typedef float f32x4 __attribute__((ext_vector_type(4)));
typedef unsigned short u16x8 __attribute__((ext_vector_type(8)));

__device__ __forceinline__ float bf2f(unsigned short u) {
    union { unsigned int i; float f; } c; c.i = ((unsigned int)u) << 16; return c.f;
}
__device__ __forceinline__ unsigned short f2bf(float f) {
    union { float f; unsigned int i; } c; c.f = f;
    unsigned int r = c.i + 0x7FFFu + ((c.i >> 16) & 1u);  // RTN-even
    return (unsigned short)(r >> 16);
}

// ---------------- cos/sin tables for RoPE ----------------
__global__ void rope_tables_k(const float* __restrict__ freqs,
                              float* __restrict__ ctab, float* __restrict__ stab, int n) {
    int i = blockIdx.x * blockDim.x + threadIdx.x;
    if (i < n) { float f = freqs[i]; ctab[i] = cosf(f); stab[i] = sinf(f); }
}

// ---------------- fp32 -> bf16 cast (vectorized) ----------------
__global__ void cast_bf16_k(const float* __restrict__ in, unsigned short* __restrict__ out, int n4) {
    int stride = gridDim.x * blockDim.x;
    for (int i = blockIdx.x * blockDim.x + threadIdx.x; i < n4; i += stride) {
        float4 v = reinterpret_cast<const float4*>(in)[i];
        ushort4 o;
        o.x = f2bf(v.x); o.y = f2bf(v.y); o.z = f2bf(v.z); o.w = f2bf(v.w);
        reinterpret_cast<ushort4*>(out)[i] = o;
    }
}

// ================= GEMM v2: 256x256 tile, 8 waves (2Mx4N), BK=32 =================
// C[M,N] = A[M,K] * B[N,K]^T, bf16 in, bf16 out. Triple-buffered LDS (96KB),
// counted vmcnt(4) + raw s_barrier (T4), XOR chunk swizzle (T2), setprio (T5).
// Stage tile t+2 while computing tile t. 2 phases x 16 MFMA per K-tile.
__global__ __launch_bounds__(512, 2) void gemm256_k(
    const unsigned short* __restrict__ A,
    const unsigned short* __restrict__ Bm,
    unsigned short* __restrict__ C,
    int M, int N, int K)
{
    __shared__ __align__(16) unsigned short ldsA[3 * 256 * 32];  // 48 KiB
    __shared__ __align__(16) unsigned short ldsB[3 * 256 * 32];  // 48 KiB

    const int tid  = threadIdx.x;
    const int wave = tid >> 6;
    const int lane = tid & 63;
    const int wm = wave >> 2;          // 0..1  (M direction, 128 rows each)
    const int wn = wave & 3;           // 0..3  (N direction, 64 cols each)
    const int g  = lane >> 4;          // k-chunk group 0..3
    const int ro = lane & 15;
    const int brow = blockIdx.x * 256;
    const int bcol = blockIdx.y * 256;
    const int NT = K >> 5;             // K-tiles of 32

    f32x4 acc[8][4] = {};

    // stage K-tile (rows r of A tile / B tile, 32 k each) into buffer sbuf.
    // LDS linear dest: idx (16B units) = j*512 + wave*64 + lane -> row=idx>>2, ch=idx&3.
    // Global source chunk = ch ^ (row&3)  (inverse of the read-side swizzle).
    auto stage = [&](int sbuf, int kt) {
        #pragma unroll
        for (int j = 0; j < 2; ++j) {
            const int idx = j * 512 + wave * 64 + lane;
            const int row = idx >> 2, ch = idx & 3;
            const int gch = ch ^ (row & 3);
            __builtin_amdgcn_global_load_lds(
                (const __attribute__((address_space(1))) void*)(
                    A + (size_t)(brow + row) * K + kt + gch * 8),
                (__attribute__((address_space(3))) void*)(
                    ldsA + sbuf * (256 * 32) + (j * 512 + wave * 64) * 8),
                16, 0, 0);
            __builtin_amdgcn_global_load_lds(
                (const __attribute__((address_space(1))) void*)(
                    Bm + (size_t)(bcol + row) * K + kt + gch * 8),
                (__attribute__((address_space(3))) void*)(
                    ldsB + sbuf * (256 * 32) + (j * 512 + wave * 64) * 8),
                16, 0, 0);
        }
    };

    // fragment reads (swizzled): row's k-chunk g lives at LDS chunk g^(row&3)
    auto rdA = [&](int buf, int mi) -> bf16x8 {
        const int row = wm * 128 + mi * 16 + ro;
        const int ch = g ^ (row & 3);
        return *reinterpret_cast<const bf16x8*>(ldsA + buf * (256 * 32) + row * 32 + ch * 8);
    };
    auto rdB = [&](int buf, int ni) -> bf16x8 {
        const int row = wn * 64 + ni * 16 + ro;
        const int ch = g ^ (row & 3);
        return *reinterpret_cast<const bf16x8*>(ldsB + buf * (256 * 32) + row * 32 + ch * 8);
    };

    stage(0, 0);
    stage(1, 32);

    int cb = 0, sb = 2;
    for (int t = 0; t < NT; ++t) {
        if (t + 2 < NT) asm volatile("s_waitcnt vmcnt(4)" ::: "memory");
        else            asm volatile("s_waitcnt vmcnt(0)" ::: "memory");
        __builtin_amdgcn_s_barrier();
        __builtin_amdgcn_sched_barrier(0);

        bf16x8 af[4], bfr[4];
        // ---- phase 0: m-frags 0..3 (+ B frags, + stage tile t+2) ----
        #pragma unroll
        for (int i = 0; i < 4; ++i) af[i] = rdA(cb, i);
        #pragma unroll
        for (int i = 0; i < 4; ++i) bfr[i] = rdB(cb, i);
        if (t + 2 < NT) stage(sb, (t + 2) * 32);
        __builtin_amdgcn_s_setprio(1);
        #pragma unroll
        for (int mi = 0; mi < 4; ++mi)
            #pragma unroll
            for (int ni = 0; ni < 4; ++ni)
                acc[mi][ni] = __builtin_amdgcn_mfma_f32_16x16x32_bf16(af[mi], bfr[ni], acc[mi][ni], 0, 0, 0);
        __builtin_amdgcn_s_setprio(0);

        // ---- phase 1: m-frags 4..7 ----
        #pragma unroll
        for (int i = 0; i < 4; ++i) af[i] = rdA(cb, 4 + i);
        __builtin_amdgcn_s_setprio(1);
        #pragma unroll
        for (int mi = 0; mi < 4; ++mi)
            #pragma unroll
            for (int ni = 0; ni < 4; ++ni)
                acc[4 + mi][ni] = __builtin_amdgcn_mfma_f32_16x16x32_bf16(af[mi], bfr[ni], acc[4 + mi][ni], 0, 0, 0);
        __builtin_amdgcn_s_setprio(0);

        cb = (cb == 2) ? 0 : cb + 1;
        sb = (sb == 2) ? 0 : sb + 1;
    }

    // epilogue: C/D layout col=lane&15, row=(lane>>4)*4+reg
    const int rg = g * 4;
    #pragma unroll
    for (int mi = 0; mi < 8; ++mi) {
        #pragma unroll
        for (int r = 0; r < 4; ++r) {
            const int row = brow + wm * 128 + mi * 16 + rg + r;
            const size_t base = (size_t)row * N + bcol + wn * 64;
            #pragma unroll
            for (int ni = 0; ni < 4; ++ni)
                C[base + ni * 16 + ro] = f2bf(acc[mi][ni][r]);
        }
    }
}

// ---------------- GEMM (m97 128x128): C[M,N] = A[M,K] * B[N,K]^T ----
template <typename OutT>
__global__ __launch_bounds__(256) void gemm_bt_k(
    const unsigned short* __restrict__ A,
    const unsigned short* __restrict__ Bm,
    OutT* __restrict__ C,
    int M, int N, int K)
{
    constexpr int BK = 32;
    __shared__ __align__(16) unsigned short ldsA[128 * BK];
    __shared__ __align__(16) unsigned short ldsB[128 * BK];

    const int tid  = threadIdx.x;
    const int wave = tid >> 6;
    const int lane = tid & 63;
    const int brow = blockIdx.x * 128;
    const int bcol = blockIdx.y * 128;
    const int wr = (wave >> 1) * 64;   // wave row offset in tile
    const int wc = (wave & 1) * 64;    // wave col offset in tile

    f32x4 acc[4][4] = {};

    const int kc = (lane & 3) * 8;     // k element offset for staging lane

    for (int kt = 0; kt < K; kt += BK) {
        __syncthreads();
        #pragma unroll
        for (int j = 0; j < 2; ++j) {
            const int i = wave * 2 + j;                 // 8 wave-instructions, 1KB each
            const int r = i * 16 + (lane >> 2);         // tile row staged by this lane
            __builtin_amdgcn_global_load_lds(
                (const __attribute__((address_space(1))) void*)(A + (size_t)(brow + r) * K + kt + kc),
                (__attribute__((address_space(3))) void*)(ldsA + i * 512),
                16, 0, 0);
            __builtin_amdgcn_global_load_lds(
                (const __attribute__((address_space(1))) void*)(Bm + (size_t)(bcol + r) * K + kt + kc),
                (__attribute__((address_space(3))) void*)(ldsB + i * 512),
                16, 0, 0);
        }
        __syncthreads();

        const int ro = lane & 15;
        const int ko = (lane >> 4) * 8;
        bf16x8 af[4], bfr[4];
        #pragma unroll
        for (int mi = 0; mi < 4; ++mi)
            af[mi] = *reinterpret_cast<const bf16x8*>(ldsA + (wr + mi * 16 + ro) * BK + ko);
        #pragma unroll
        for (int ni = 0; ni < 4; ++ni)
            bfr[ni] = *reinterpret_cast<const bf16x8*>(ldsB + (wc + ni * 16 + ro) * BK + ko);
        #pragma unroll
        for (int mi = 0; mi < 4; ++mi)
            #pragma unroll
            for (int ni = 0; ni < 4; ++ni)
                acc[mi][ni] = __builtin_amdgcn_mfma_f32_16x16x32_bf16(af[mi], bfr[ni], acc[mi][ni], 0, 0, 0);
    }

    // epilogue: C/D layout col=lane&15, row=(lane>>4)*4+reg  (m89-verified)
    const int ro = lane & 15;
    const int rg = (lane >> 4) * 4;
    #pragma unroll
    for (int mi = 0; mi < 4; ++mi) {
        #pragma unroll
        for (int r = 0; r < 4; ++r) {
            const int row = brow + wr + mi * 16 + rg + r;
            const size_t base = (size_t)row * N + bcol + wc;
            #pragma unroll
            for (int ni = 0; ni < 4; ++ni) {
                float v = acc[mi][ni][r];
                if constexpr (sizeof(OutT) == 2) C[base + ni * 16 + ro] = f2bf(v);
                else                             C[base + ni * 16 + ro] = v;
            }
        }
    }
}

// ---------------- per-head RMSNorm + RoPE on Q/K, relayout to [b*H+h][s][c] ----
// one wave per (m=s*B+b, h); 2 channels per lane (c = 2*lane, 2*lane+1)
__global__ __launch_bounds__(256) void qk_post_k(
    const unsigned short* __restrict__ raw,   // [M][ld], head h at col h*C
    int ld,
    const float* __restrict__ wscale,         // [C]
    const float* __restrict__ ctab, const float* __restrict__ stab, // [S][C]
    unsigned short* __restrict__ outp)        // [B*H][S][C]
{
    const int gw = blockIdx.x * 4 + (threadIdx.x >> 6);
    const int lane = threadIdx.x & 63;
    const int m = gw >> 4;          // row in [0, M)
    const int h = gw & 15;
    const int s = m >> 1, b = m & 1;
    const int c0 = lane * 2;

    const unsigned short* src = raw + (size_t)m * ld + h * C_DIM + c0;
    unsigned int packed = *reinterpret_cast<const unsigned int*>(src);
    float x0 = bf2f((unsigned short)(packed & 0xFFFF));
    float x1 = bf2f((unsigned short)(packed >> 16));

    float ss = x0 * x0 + x1 * x1;
    #pragma unroll
    for (int off = 32; off; off >>= 1) ss += __shfl_xor(ss, off);
    const float rs = rsqrtf(ss * (1.0f / C_DIM) + 1e-6f);

    float n0 = x0 * rs * wscale[c0];
    float n1 = x1 * rs * wscale[c0 + 1];
    // RoPE: partner channel c +/- 64 lives in lane^32
    float p0 = __shfl_xor(n0, 32);
    float p1 = __shfl_xor(n1, 32);
    const float sgn = (lane < 32) ? -1.0f : 1.0f;
    const float* cp = ctab + (size_t)s * C_DIM + c0;
    const float* sp = stab + (size_t)s * C_DIM + c0;
    float o0 = n0 * cp[0] + sgn * p0 * sp[0];
    float o1 = n1 * cp[1] + sgn * p1 * sp[1];

    unsigned int opk = (unsigned int)f2bf(o0) | ((unsigned int)f2bf(o1) << 16);
    *reinterpret_cast<unsigned int*>(
        outp + ((size_t)(b * H_DIM + h) * S_DIM + s) * C_DIM + c0) = opk;
}

// ---------------- V relayout+transpose: raw [M][ld] (V at col 2*D) -> Vt [b*H+h][C][S] ----
__global__ __launch_bounds__(256) void v_transpose_k(
    const unsigned short* __restrict__ raw, int ld, int colbase,
    unsigned short* __restrict__ Vt)
{
    __shared__ __align__(16) unsigned short tile[64][136];  // +8 pad
    const int bh = blockIdx.y;
    const int b = bh >> 4, h = bh & 15;
    const int sbase = blockIdx.x * 64;
    const int t = threadIdx.x;

    {   // load 64 s-rows x 128 c, coalesced 16B
        const int s = t >> 2, cq = (t & 3) * 32;
        const unsigned short* src = raw + (size_t)((sbase + s) * B_DIM + b) * ld + colbase + h * C_DIM + cq;
        #pragma unroll
        for (int j = 0; j < 4; ++j) {
            u16x8 v = *reinterpret_cast<const u16x8*>(src + j * 8);
            *reinterpret_cast<u16x8*>(&tile[s][cq + j * 8]) = v;
        }
    }
    __syncthreads();
    {   // write 128 c-rows x 64 s, coalesced 16B
        const int c = t >> 1, sh = (t & 1) * 32;
        unsigned short* dst = Vt + ((size_t)bh * C_DIM + c) * S_DIM + sbase + sh;
        #pragma unroll
        for (int j = 0; j < 32; j += 8) {
            u16x8 o;
            #pragma unroll
            for (int e = 0; e < 8; ++e) o[e] = tile[sh + j + e][c];
            *reinterpret_cast<u16x8*>(dst + j) = o;
        }
    }
}

// ---------------- flash attention v3: cooperative LDS-staged, double-buffered ----
// grid (S/128, B*H); 8 waves/block, each wave owns 16 q-rows; KVBLK=64 per step.
// LDS = 80KB exactly -> 2 blocks/CU (cross-block latency hiding).
// K tile [64][128], V tile [128][64], P tile [16][64] all XOR-chunk-swizzled.
__global__ __launch_bounds__(512, 4) void attn_k(
    const unsigned short* __restrict__ Qb,
    const unsigned short* __restrict__ Kb,
    const unsigned short* __restrict__ Vt,
    unsigned short* __restrict__ Ao)          // [M][D], row = s*B+b, col = h*C+c
{
    __shared__ __align__(16) unsigned short ldsK[2][64 * 128];   // 32 KiB
    __shared__ __align__(16) unsigned short ldsV[2][128 * 64];   // 32 KiB
    __shared__ __align__(16) unsigned short plds[8][16 * 64];    // 16 KiB, per-wave P (swizzled)

    const int bh = blockIdx.y;
    const int wave = threadIdx.x >> 6;
    const int lane = threadIdx.x & 63;
    const int qbase = blockIdx.x * 128 + wave * 16;
    const int g  = lane >> 4;       // k-slot group 0..3
    const int ro = lane & 15;
    const int ko = g * 8;
    const int rg = g * 4;

    const unsigned short* Q  = Qb + (size_t)bh * S_DIM * C_DIM;
    const unsigned short* Km = Kb + (size_t)bh * S_DIM * C_DIM;
    const unsigned short* V  = Vt + (size_t)bh * C_DIM * S_DIM;
    unsigned short* pw = &plds[wave][0];

    bf16x8 qf[4];
    #pragma unroll
    for (int kf = 0; kf < 4; ++kf)
        qf[kf] = *reinterpret_cast<const bf16x8*>(Q + (size_t)(qbase + ro) * C_DIM + kf * 32 + ko);

    // stage K[kb..kb+64)x128 and V[0..128)x[kb..kb+64) into buffer bufi.
    auto stage = [&](int bufi, int kb) {
        #pragma unroll
        for (int j = 0; j < 2; ++j) {
            const int idx = (wave * 2 + j) * 64 + lane;
            {   // K tile: row = idx>>4 (64 rows), chunk = idx&15 (256B rows)
                const int row = idx >> 4, ch = idx & 15;
                const int sch = (ch & 8) | ((ch ^ row) & 7);
                __builtin_amdgcn_global_load_lds(
                    (const __attribute__((address_space(1))) void*)(
                        Km + (size_t)(kb + row) * C_DIM + sch * 8),
                    (__attribute__((address_space(3))) void*)(
                        &ldsK[bufi][(wave * 2 + j) * 512]),
                    16, 0, 0);
            }
            {   // V tile: row = idx>>3 (128 rows), chunk = idx&7 (128B rows)
                const int row = idx >> 3, ch = idx & 7;
                const int sch = (ch ^ row) & 7;
                __builtin_amdgcn_global_load_lds(
                    (const __attribute__((address_space(1))) void*)(
                        V + (size_t)row * S_DIM + kb + sch * 8),
                    (__attribute__((address_space(3))) void*)(
                        &ldsV[bufi][(wave * 2 + j) * 512]),
                    16, 0, 0);
            }
        }
    };

    f32x4 of[8] = {};
    float mrow[4] = {-1e30f, -1e30f, -1e30f, -1e30f};
    float lrow[4] = {0.f, 0.f, 0.f, 0.f};
    const float inv_scale = 0.08838834764831845f;  // 1/sqrt(128)

    stage(0, 0);
    asm volatile("s_waitcnt vmcnt(0)" ::: "memory");
    __syncthreads();

    int cur = 0;
    for (int kb = 0; kb < S_DIM; kb += 64) {
        if (kb + 64 < S_DIM) stage(cur ^ 1, kb + 64);

        // ---- QK^T: 64 k-cols as 4 n-fragments ----
        f32x4 s4[4] = {};
        __builtin_amdgcn_s_setprio(1);
        #pragma unroll
        for (int nc = 0; nc < 4; ++nc) {
            const int r_loc = nc * 16 + ro;
            #pragma unroll
            for (int kf = 0; kf < 4; ++kf) {
                const int c = kf * 4 + g;
                const int sch = (c & 8) | ((c ^ r_loc) & 7);
                bf16x8 kfr = *reinterpret_cast<const bf16x8*>(
                    &ldsK[cur][r_loc * 128 + sch * 8]);
                s4[nc] = __builtin_amdgcn_mfma_f32_16x16x32_bf16(qf[kf], kfr, s4[nc], 0, 0, 0);
            }
        }
        __builtin_amdgcn_s_setprio(0);

        // ---- online softmax over the 64 columns ----
        #pragma unroll
        for (int nc = 0; nc < 4; ++nc)
            #pragma unroll
            for (int r = 0; r < 4; ++r) s4[nc][r] *= inv_scale;

        float mx[4];
        #pragma unroll
        for (int r = 0; r < 4; ++r)
            mx[r] = fmaxf(fmaxf(s4[0][r], s4[1][r]), fmaxf(s4[2][r], s4[3][r]));
        #pragma unroll
        for (int off = 1; off < 16; off <<= 1)
            #pragma unroll
            for (int r = 0; r < 4; ++r) mx[r] = fmaxf(mx[r], __shfl_xor(mx[r], off));

        // T13 defer-max: only rescale when the running max grows by >8
        float mg = 0.f;
        #pragma unroll
        for (int r = 0; r < 4; ++r) mg = fmaxf(mg, mx[r] - mrow[r]);
        if (__any(mg > 8.0f)) {
            float resc[4];
            #pragma unroll
            for (int r = 0; r < 4; ++r) {
                float mnew = fmaxf(mrow[r], mx[r]);
                resc[r] = __expf(mrow[r] - mnew);
                mrow[r] = mnew;
                lrow[r] *= resc[r];
            }
            #pragma unroll
            for (int nf = 0; nf < 8; ++nf)
                #pragma unroll
                for (int r = 0; r < 4; ++r) of[nf][r] *= resc[r];
        }

        float ladd[4];
        #pragma unroll
        for (int r = 0; r < 4; ++r) {
            float p0 = __expf(s4[0][r] - mrow[r]);
            float p1 = __expf(s4[1][r] - mrow[r]);
            float p2 = __expf(s4[2][r] - mrow[r]);
            float p3 = __expf(s4[3][r] - mrow[r]);
            s4[0][r] = p0; s4[1][r] = p1; s4[2][r] = p2; s4[3][r] = p3;
            ladd[r] = (p0 + p1) + (p2 + p3);
        }
        #pragma unroll
        for (int off = 1; off < 16; off <<= 1)
            #pragma unroll
            for (int r = 0; r < 4; ++r) ladd[r] += __shfl_xor(ladd[r], off);
        #pragma unroll
        for (int r = 0; r < 4; ++r) lrow[r] += ladd[r];

        // ---- P (C-frag layout) -> per-wave swizzled LDS -> A-frag layout ----
        #pragma unroll
        for (int nc = 0; nc < 4; ++nc)
            #pragma unroll
            for (int r = 0; r < 4; ++r) {
                const int q = rg + r;
                const int k = nc * 16 + ro;
                pw[q * 64 + (((k >> 3) ^ (q & 7)) << 3) + (k & 7)] = f2bf(s4[nc][r]);
            }
        __asm__ volatile("" ::: "memory");

        // ---- PV: 2 k-slices of 32 ----
        __builtin_amdgcn_s_setprio(1);
        #pragma unroll
        for (int ks = 0; ks < 2; ++ks) {
            const int psch = (ks * 4 + g) ^ (ro & 7);
            bf16x8 pa = *reinterpret_cast<const bf16x8*>(&pw[ro * 64 + psch * 8]);
            #pragma unroll
            for (int nf = 0; nf < 8; ++nf) {
                const int vr = nf * 16 + ro;
                const int c = ks * 4 + g;
                const int sch = (c ^ vr) & 7;
                bf16x8 vf = *reinterpret_cast<const bf16x8*>(&ldsV[cur][vr * 64 + sch * 8]);
                of[nf] = __builtin_amdgcn_mfma_f32_16x16x32_bf16(pa, vf, of[nf], 0, 0, 0);
            }
        }
        __builtin_amdgcn_s_setprio(0);

        asm volatile("s_waitcnt vmcnt(0)" ::: "memory");
        __syncthreads();
        cur ^= 1;
    }

    const int b = bh >> 4, h = bh & 15;
    float inv_l[4];
    #pragma unroll
    for (int r = 0; r < 4; ++r) inv_l[r] = 1.0f / lrow[r];
    #pragma unroll
    for (int r = 0; r < 4; ++r) {
        const int srow = qbase + rg + r;
        unsigned short* dst = Ao + (size_t)(srow * B_DIM + b) * D_DIM + h * C_DIM;
        #pragma unroll
        for (int nf = 0; nf < 8; ++nf)
            dst[nf * 16 + ro] = f2bf(of[nf][r] * inv_l[r]);
    }
}

extern "C" void kernel_launch(void* const* d_in, const int* in_sizes, int n_in,
                              void* d_out, int out_size, void* d_ws, size_t ws_size,
                              hipStream_t stream) {
    const float* x       = (const float*)d_in[0];
    const float* rope    = (const float*)d_in[1];
    const float* Wq      = (const float*)d_in[2];
    const float* Wk      = (const float*)d_in[3];
    const float* Wv      = (const float*)d_in[4];
    const float* Wo      = (const float*)d_in[5];
    const float* q_scale = (const float*)d_in[6];
    const float* k_scale = (const float*)d_in[7];
    float* out = (float*)d_out;

    char* w = (char*)d_ws;
    size_t off = 0;
    auto alloc = [&](size_t bytes) {
        char* p = w + off; off += (bytes + 255) & ~(size_t)255; return p;
    };
    unsigned short* xb   = (unsigned short*)alloc((size_t)M_DIM * D_DIM * 2);  // 16 MiB
    unsigned short* Wqb  = (unsigned short*)alloc((size_t)D_DIM * D_DIM * 2);  // contiguous
    unsigned short* Wkb  = (unsigned short*)alloc((size_t)D_DIM * D_DIM * 2);  //   Wq|Wk|Wv
    unsigned short* Wvb  = (unsigned short*)alloc((size_t)D_DIM * D_DIM * 2);
    unsigned short* Wob  = (unsigned short*)alloc((size_t)D_DIM * D_DIM * 2);
    unsigned short* rawQKV = (unsigned short*)alloc((size_t)M_DIM * 3 * D_DIM * 2); // [M][6144]
    unsigned short* Qb   = (unsigned short*)alloc((size_t)M_DIM * D_DIM * 2);
    unsigned short* Kb   = (unsigned short*)alloc((size_t)M_DIM * D_DIM * 2);
    unsigned short* Vt   = (unsigned short*)alloc((size_t)M_DIM * D_DIM * 2);
    float* ctab = (float*)alloc((size_t)S_DIM * C_DIM * 4);
    float* stab = (float*)alloc((size_t)S_DIM * C_DIM * 4);
    unsigned short* Ao = rawQKV;  // reuse (rawQKV dead before attention writes)
    (void)Wkb; (void)Wvb; (void)ws_size; (void)in_sizes; (void)n_in; (void)out_size;

    const int NQKV = 3 * D_DIM;  // 6144

    rope_tables_k<<<(S_DIM * C_DIM + 255) / 256, 256, 0, stream>>>(rope, ctab, stab, S_DIM * C_DIM);
    cast_bf16_k<<<1024, 256, 0, stream>>>(x,  xb,  M_DIM * D_DIM / 4);
    cast_bf16_k<<<1024, 256, 0, stream>>>(Wq, Wqb, D_DIM * D_DIM / 4);
    cast_bf16_k<<<1024, 256, 0, stream>>>(Wk, Wkb, D_DIM * D_DIM / 4);
    cast_bf16_k<<<1024, 256, 0, stream>>>(Wv, Wvb, D_DIM * D_DIM / 4);
    cast_bf16_k<<<1024, 256, 0, stream>>>(Wo, Wob, D_DIM * D_DIM / 4);

    // fused QKV projection: [4096,2048] x [6144,2048]^T  (256x256 8-phase-style)
    gemm256_k<<<dim3(M_DIM / 256, NQKV / 256), 512, 0, stream>>>(
        xb, Wqb, rawQKV, M_DIM, NQKV, D_DIM);

    qk_post_k<<<M_DIM * H_DIM / 4, 256, 0, stream>>>(rawQKV,              NQKV, q_scale, ctab, stab, Qb);
    qk_post_k<<<M_DIM * H_DIM / 4, 256, 0, stream>>>(rawQKV + D_DIM,      NQKV, k_scale, ctab, stab, Kb);
    v_transpose_k<<<dim3(S_DIM / 64, B_DIM * H_DIM), 256, 0, stream>>>(rawQKV, NQKV, 2 * D_DIM, Vt);

    attn_k<<<dim3(S_DIM / 128, B_DIM * H_DIM), 512, 0, stream>>>(Qb, Kb, Vt, Ao);

    // out projection: [4096,2048] x [2048,2048]^T -> fp32 d_out
    gemm_bt_k<float><<<dim3(M_DIM / 128, D_DIM / 128), 256, 0, stream>>>(
        Ao, Wob, out, M_DIM, D_DIM, D_DIM);
}

// Round 5
// 379.133 us; speedup vs baseline: 2.4227x; 1.0063x over previous
//
#include <hip/hip_runtime.h>
#include <stdint.h>

#define S_DIM 2048
#define B_DIM 2
#define D_DIM 2048
#define H_DIM 16
#define C_DIM 128
#define M_DIM 4096   // S*B rows, row = s*B + b

typedef __bf16 bf16x8 __attribute__((ext_vector_type(8)));
typedef float f32x4 __attribute__((ext_vector_type(4)));
typedef unsigned short u16x8 __attribute__((ext_vector_type(8)));

__device__ __forceinline__ float bf2f(unsigned short u) {
    union { unsigned int i; float f; } c; c.i = ((unsigned int)u) << 16; return c.f;
}
__device__ __forceinline__ unsigned short f2bf(float f) {
    union { float f; unsigned int i; } c; c.f = f;
    unsigned int r = c.i + 0x7FFFu + ((c.i >> 16) & 1u);  // RTN-even
    return (unsigned short)(r >> 16);
}

// ---------------- cos/sin tables for RoPE ----------------
__global__ void rope_tables_k(const float* __restrict__ freqs,
                              float* __restrict__ ctab, float* __restrict__ stab, int n) {
    int i = blockIdx.x * blockDim.x + threadIdx.x;
    if (i < n) { float f = freqs[i]; ctab[i] = cosf(f); stab[i] = sinf(f); }
}

// ---------------- fp32 -> bf16 cast (vectorized) ----------------
__global__ void cast_bf16_k(const float* __restrict__ in, unsigned short* __restrict__ out, int n4) {
    int stride = gridDim.x * blockDim.x;
    for (int i = blockIdx.x * blockDim.x + threadIdx.x; i < n4; i += stride) {
        float4 v = reinterpret_cast<const float4*>(in)[i];
        ushort4 o;
        o.x = f2bf(v.x); o.y = f2bf(v.y); o.z = f2bf(v.z); o.w = f2bf(v.w);
        reinterpret_cast<ushort4*>(out)[i] = o;
    }
}

// ---------------- 4 weight matrices fp32 -> bf16 in one launch ----------------
// each matrix is D*D floats; D*D/4 float4's = 2^20 exactly (sel = i>>20).
__global__ void cast_w4_k(const float* __restrict__ w0, const float* __restrict__ w1,
                          const float* __restrict__ w2, const float* __restrict__ w3,
                          unsigned short* __restrict__ out) {
    const int n4 = (D_DIM * D_DIM) / 4;           // 1<<20
    const int total = 4 * n4;
    int stride = gridDim.x * blockDim.x;
    for (int i = blockIdx.x * blockDim.x + threadIdx.x; i < total; i += stride) {
        const int sel = i >> 20;
        const int idx = i & (n4 - 1);
        const float* src = (sel == 0) ? w0 : (sel == 1) ? w1 : (sel == 2) ? w2 : w3;
        float4 v = reinterpret_cast<const float4*>(src)[idx];
        ushort4 o;
        o.x = f2bf(v.x); o.y = f2bf(v.y); o.z = f2bf(v.z); o.w = f2bf(v.w);
        reinterpret_cast<ushort4*>(out)[i] = o;
    }
}

// ================= GEMM: 128x256 tile, 8 waves (2Mx4N, 64x64 each), BK=32 =======
// C[M,N] = A[M,K] * B[N,K]^T, bf16 in. Triple-buffered LDS (72KB -> 2 blocks/CU),
// counted vmcnt(3) + raw s_barrier (T4), XOR chunk swizzle (T2), setprio (T5),
// bijective XCD swizzle (T1; requires nwg%8==0).
template <typename OutT>
__global__ __launch_bounds__(512, 4) void gemm_bn_k(
    const unsigned short* __restrict__ A,
    const unsigned short* __restrict__ Bm,
    OutT* __restrict__ C,
    int M, int N, int K)
{
    __shared__ __align__(16) unsigned short ldsA[3 * 128 * 32];  // 24 KiB
    __shared__ __align__(16) unsigned short ldsB[3 * 256 * 32];  // 48 KiB

    const int tid  = threadIdx.x;
    const int wave = tid >> 6;
    const int lane = tid & 63;
    const int wm = wave >> 2;          // 0..1  (M, 64 rows each)
    const int wn = wave & 3;           // 0..3  (N, 64 cols each)
    const int g  = lane >> 4;          // k-chunk group 0..3
    const int ro = lane & 15;

    // T1: bijective XCD swizzle (nwg % 8 == 0 for both call sites)
    const int nwg = gridDim.x * gridDim.y;
    int lin = blockIdx.y * gridDim.x + blockIdx.x;
    lin = (lin & 7) * (nwg >> 3) + (lin >> 3);
    const int bx = lin % gridDim.x;
    const int by = lin / gridDim.x;
    const int brow = bx * 128;
    const int bcol = by * 256;
    const int NT = K >> 5;             // K-tiles of 32

    f32x4 acc[4][4] = {};

    // stage one K-tile into buffer sbuf: per-thread 1 A-chunk + 2 B-chunks.
    // LDS dest linear (16B units = thread idx); global chunk = ch ^ (row&3)
    // (inverse of read-side swizzle, rule #21 both-sides).
    auto stage = [&](int sbuf, int kt) {
        {
            const int row = tid >> 2, ch = tid & 3;
            const int gch = ch ^ (row & 3);
            __builtin_amdgcn_global_load_lds(
                (const __attribute__((address_space(1))) void*)(
                    A + (size_t)(brow + row) * K + kt + gch * 8),
                (__attribute__((address_space(3))) void*)(
                    ldsA + sbuf * (128 * 32) + (wave * 64) * 8),
                16, 0, 0);
        }
        #pragma unroll
        for (int j = 0; j < 2; ++j) {
            const int idx = j * 512 + tid;
            const int row = idx >> 2, ch = idx & 3;
            const int gch = ch ^ (row & 3);
            __builtin_amdgcn_global_load_lds(
                (const __attribute__((address_space(1))) void*)(
                    Bm + (size_t)(bcol + row) * K + kt + gch * 8),
                (__attribute__((address_space(3))) void*)(
                    ldsB + sbuf * (256 * 32) + (j * 512 + wave * 64) * 8),
                16, 0, 0);
        }
    };

    auto rdA = [&](int buf, int mi) -> bf16x8 {
        const int row = wm * 64 + mi * 16 + ro;
        const int ch = g ^ (row & 3);
        return *reinterpret_cast<const bf16x8*>(ldsA + buf * (128 * 32) + row * 32 + ch * 8);
    };
    auto rdB = [&](int buf, int ni) -> bf16x8 {
        const int row = wn * 64 + ni * 16 + ro;
        const int ch = g ^ (row & 3);
        return *reinterpret_cast<const bf16x8*>(ldsB + buf * (256 * 32) + row * 32 + ch * 8);
    };

    stage(0, 0);
    stage(1, 32);

    int cb = 0, sb = 2;
    for (int t = 0; t < NT; ++t) {
        if (t + 2 < NT) asm volatile("s_waitcnt vmcnt(3)" ::: "memory");
        else            asm volatile("s_waitcnt vmcnt(0)" ::: "memory");
        __builtin_amdgcn_s_barrier();
        __builtin_amdgcn_sched_barrier(0);

        bf16x8 bfr[4];
        #pragma unroll
        for (int i = 0; i < 4; ++i) bfr[i] = rdB(cb, i);
        if (t + 2 < NT) stage(sb, (t + 2) * 32);

        __builtin_amdgcn_s_setprio(1);
        #pragma unroll
        for (int mi = 0; mi < 4; ++mi) {
            bf16x8 af = rdA(cb, mi);
            #pragma unroll
            for (int ni = 0; ni < 4; ++ni)
                acc[mi][ni] = __builtin_amdgcn_mfma_f32_16x16x32_bf16(af, bfr[ni], acc[mi][ni], 0, 0, 0);
        }
        __builtin_amdgcn_s_setprio(0);

        cb = (cb == 2) ? 0 : cb + 1;
        sb = (sb == 2) ? 0 : sb + 1;
    }

    // epilogue: C/D layout col=lane&15, row=(lane>>4)*4+reg  (m89-verified)
    const int rg = g * 4;
    #pragma unroll
    for (int mi = 0; mi < 4; ++mi) {
        #pragma unroll
        for (int r = 0; r < 4; ++r) {
            const int row = brow + wm * 64 + mi * 16 + rg + r;
            const size_t base = (size_t)row * N + bcol + wn * 64;
            #pragma unroll
            for (int ni = 0; ni < 4; ++ni) {
                float v = acc[mi][ni][r];
                if constexpr (sizeof(OutT) == 2) C[base + ni * 16 + ro] = f2bf(v);
                else                             C[base + ni * 16 + ro] = v;
            }
        }
    }
}

// ---------------- per-head RMSNorm + RoPE on Q/K, relayout to [b*H+h][s][c] ----
// one wave per (m=s*B+b, h); 2 channels per lane. post_mul folds 1/sqrt(C) into Q.
__global__ __launch_bounds__(256) void qk_post_k(
    const unsigned short* __restrict__ raw,   // [M][ld], head h at col h*C
    int ld,
    const float* __restrict__ wscale,         // [C]
    const float* __restrict__ ctab, const float* __restrict__ stab, // [S][C]
    unsigned short* __restrict__ outp,        // [B*H][S][C]
    float post_mul)
{
    const int gw = blockIdx.x * 4 + (threadIdx.x >> 6);
    const int lane = threadIdx.x & 63;
    const int m = gw >> 4;          // row in [0, M)
    const int h = gw & 15;
    const int s = m >> 1, b = m & 1;
    const int c0 = lane * 2;

    const unsigned short* src = raw + (size_t)m * ld + h * C_DIM + c0;
    unsigned int packed = *reinterpret_cast<const unsigned int*>(src);
    float x0 = bf2f((unsigned short)(packed & 0xFFFF));
    float x1 = bf2f((unsigned short)(packed >> 16));

    float ss = x0 * x0 + x1 * x1;
    #pragma unroll
    for (int off = 32; off; off >>= 1) ss += __shfl_xor(ss, off);
    const float rs = rsqrtf(ss * (1.0f / C_DIM) + 1e-6f);

    float n0 = x0 * rs * wscale[c0];
    float n1 = x1 * rs * wscale[c0 + 1];
    // RoPE: partner channel c +/- 64 lives in lane^32
    float p0 = __shfl_xor(n0, 32);
    float p1 = __shfl_xor(n1, 32);
    const float sgn = (lane < 32) ? -1.0f : 1.0f;
    const float* cp = ctab + (size_t)s * C_DIM + c0;
    const float* sp = stab + (size_t)s * C_DIM + c0;
    float o0 = (n0 * cp[0] + sgn * p0 * sp[0]) * post_mul;
    float o1 = (n1 * cp[1] + sgn * p1 * sp[1]) * post_mul;

    unsigned int opk = (unsigned int)f2bf(o0) | ((unsigned int)f2bf(o1) << 16);
    *reinterpret_cast<unsigned int*>(
        outp + ((size_t)(b * H_DIM + h) * S_DIM + s) * C_DIM + c0) = opk;
}

// ---------------- V relayout+transpose: raw [M][ld] (V at col 2*D) -> Vt [b*H+h][C][S] ----
__global__ __launch_bounds__(256) void v_transpose_k(
    const unsigned short* __restrict__ raw, int ld, int colbase,
    unsigned short* __restrict__ Vt)
{
    __shared__ __align__(16) unsigned short tile[64][136];  // +8 pad
    const int bh = blockIdx.y;
    const int b = bh >> 4, h = bh & 15;
    const int sbase = blockIdx.x * 64;
    const int t = threadIdx.x;

    {   // load 64 s-rows x 128 c, coalesced 16B
        const int s = t >> 2, cq = (t & 3) * 32;
        const unsigned short* src = raw + (size_t)((sbase + s) * B_DIM + b) * ld + colbase + h * C_DIM + cq;
        #pragma unroll
        for (int j = 0; j < 4; ++j) {
            u16x8 v = *reinterpret_cast<const u16x8*>(src + j * 8);
            *reinterpret_cast<u16x8*>(&tile[s][cq + j * 8]) = v;
        }
    }
    __syncthreads();
    {   // write 128 c-rows x 64 s, coalesced 16B
        const int c = t >> 1, sh = (t & 1) * 32;
        unsigned short* dst = Vt + ((size_t)bh * C_DIM + c) * S_DIM + sbase + sh;
        #pragma unroll
        for (int j = 0; j < 32; j += 8) {
            u16x8 o;
            #pragma unroll
            for (int e = 0; e < 8; ++e) o[e] = tile[sh + j + e][c];
            *reinterpret_cast<u16x8*>(dst + j) = o;
        }
    }
}

// ---------------- flash attention v3: cooperative LDS-staged, double-buffered ----
// grid (S/128, B*H); 8 waves/block, each wave owns 16 q-rows; KVBLK=64 per step.
// LDS = 80KB exactly -> 2 blocks/CU. Q is pre-scaled by 1/sqrt(C) in qk_post.
__global__ __launch_bounds__(512, 4) void attn_k(
    const unsigned short* __restrict__ Qb,
    const unsigned short* __restrict__ Kb,
    const unsigned short* __restrict__ Vt,
    unsigned short* __restrict__ Ao)          // [M][D], row = s*B+b, col = h*C+c
{
    __shared__ __align__(16) unsigned short ldsK[2][64 * 128];   // 32 KiB
    __shared__ __align__(16) unsigned short ldsV[2][128 * 64];   // 32 KiB
    __shared__ __align__(16) unsigned short plds[8][16 * 64];    // 16 KiB, per-wave P (swizzled)

    const int bh = blockIdx.y;
    const int wave = threadIdx.x >> 6;
    const int lane = threadIdx.x & 63;
    const int qbase = blockIdx.x * 128 + wave * 16;
    const int g  = lane >> 4;       // k-slot group 0..3
    const int ro = lane & 15;
    const int ko = g * 8;
    const int rg = g * 4;

    const unsigned short* Q  = Qb + (size_t)bh * S_DIM * C_DIM;
    const unsigned short* Km = Kb + (size_t)bh * S_DIM * C_DIM;
    const unsigned short* V  = Vt + (size_t)bh * C_DIM * S_DIM;
    unsigned short* pw = &plds[wave][0];

    bf16x8 qf[4];
    #pragma unroll
    for (int kf = 0; kf < 4; ++kf)
        qf[kf] = *reinterpret_cast<const bf16x8*>(Q + (size_t)(qbase + ro) * C_DIM + kf * 32 + ko);

    // stage K[kb..kb+64)x128 and V[0..128)x[kb..kb+64) into buffer bufi.
    auto stage = [&](int bufi, int kb) {
        #pragma unroll
        for (int j = 0; j < 2; ++j) {
            const int idx = (wave * 2 + j) * 64 + lane;
            {   // K tile: row = idx>>4 (64 rows), chunk = idx&15 (256B rows)
                const int row = idx >> 4, ch = idx & 15;
                const int sch = (ch & 8) | ((ch ^ row) & 7);
                __builtin_amdgcn_global_load_lds(
                    (const __attribute__((address_space(1))) void*)(
                        Km + (size_t)(kb + row) * C_DIM + sch * 8),
                    (__attribute__((address_space(3))) void*)(
                        &ldsK[bufi][(wave * 2 + j) * 512]),
                    16, 0, 0);
            }
            {   // V tile: row = idx>>3 (128 rows), chunk = idx&7 (128B rows)
                const int row = idx >> 3, ch = idx & 7;
                const int sch = (ch ^ row) & 7;
                __builtin_amdgcn_global_load_lds(
                    (const __attribute__((address_space(1))) void*)(
                        V + (size_t)row * S_DIM + kb + sch * 8),
                    (__attribute__((address_space(3))) void*)(
                        &ldsV[bufi][(wave * 2 + j) * 512]),
                    16, 0, 0);
            }
        }
    };

    f32x4 of[8] = {};
    float mrow[4] = {-1e30f, -1e30f, -1e30f, -1e30f};
    float lrow[4] = {0.f, 0.f, 0.f, 0.f};

    stage(0, 0);
    asm volatile("s_waitcnt vmcnt(0)" ::: "memory");
    __syncthreads();

    int cur = 0;
    for (int kb = 0; kb < S_DIM; kb += 64) {
        if (kb + 64 < S_DIM) stage(cur ^ 1, kb + 64);

        // ---- QK^T: 64 k-cols as 4 n-fragments ----
        f32x4 s4[4] = {};
        __builtin_amdgcn_s_setprio(1);
        #pragma unroll
        for (int nc = 0; nc < 4; ++nc) {
            const int r_loc = nc * 16 + ro;
            #pragma unroll
            for (int kf = 0; kf < 4; ++kf) {
                const int c = kf * 4 + g;
                const int sch = (c & 8) | ((c ^ r_loc) & 7);
                bf16x8 kfr = *reinterpret_cast<const bf16x8*>(
                    &ldsK[cur][r_loc * 128 + sch * 8]);
                s4[nc] = __builtin_amdgcn_mfma_f32_16x16x32_bf16(qf[kf], kfr, s4[nc], 0, 0, 0);
            }
        }
        __builtin_amdgcn_s_setprio(0);

        // ---- online softmax over the 64 columns (scores pre-scaled) ----
        float mx[4];
        #pragma unroll
        for (int r = 0; r < 4; ++r)
            mx[r] = fmaxf(fmaxf(s4[0][r], s4[1][r]), fmaxf(s4[2][r], s4[3][r]));
        #pragma unroll
        for (int off = 1; off < 16; off <<= 1)
            #pragma unroll
            for (int r = 0; r < 4; ++r) mx[r] = fmaxf(mx[r], __shfl_xor(mx[r], off));

        // T13 defer-max: only rescale when the running max grows by >8
        float mg = 0.f;
        #pragma unroll
        for (int r = 0; r < 4; ++r) mg = fmaxf(mg, mx[r] - mrow[r]);
        if (__any(mg > 8.0f)) {
            float resc[4];
            #pragma unroll
            for (int r = 0; r < 4; ++r) {
                float mnew = fmaxf(mrow[r], mx[r]);
                resc[r] = __expf(mrow[r] - mnew);
                mrow[r] = mnew;
                lrow[r] *= resc[r];
            }
            #pragma unroll
            for (int nf = 0; nf < 8; ++nf)
                #pragma unroll
                for (int r = 0; r < 4; ++r) of[nf][r] *= resc[r];
        }

        float ladd[4];
        #pragma unroll
        for (int r = 0; r < 4; ++r) {
            float p0 = __expf(s4[0][r] - mrow[r]);
            float p1 = __expf(s4[1][r] - mrow[r]);
            float p2 = __expf(s4[2][r] - mrow[r]);
            float p3 = __expf(s4[3][r] - mrow[r]);
            s4[0][r] = p0; s4[1][r] = p1; s4[2][r] = p2; s4[3][r] = p3;
            ladd[r] = (p0 + p1) + (p2 + p3);
        }
        #pragma unroll
        for (int off = 1; off < 16; off <<= 1)
            #pragma unroll
            for (int r = 0; r < 4; ++r) ladd[r] += __shfl_xor(ladd[r], off);
        #pragma unroll
        for (int r = 0; r < 4; ++r) lrow[r] += ladd[r];

        // ---- P (C-frag layout) -> per-wave swizzled LDS -> A-frag layout ----
        #pragma unroll
        for (int nc = 0; nc < 4; ++nc)
            #pragma unroll
            for (int r = 0; r < 4; ++r) {
                const int q = rg + r;
                const int k = nc * 16 + ro;
                pw[q * 64 + (((k >> 3) ^ (q & 7)) << 3) + (k & 7)] = f2bf(s4[nc][r]);
            }
        __asm__ volatile("" ::: "memory");

        // ---- PV: 2 k-slices of 32 ----
        __builtin_amdgcn_s_setprio(1);
        #pragma unroll
        for (int ks = 0; ks < 2; ++ks) {
            const int psch = (ks * 4 + g) ^ (ro & 7);
            bf16x8 pa = *reinterpret_cast<const bf16x8*>(&pw[ro * 64 + psch * 8]);
            #pragma unroll
            for (int nf = 0; nf < 8; ++nf) {
                const int vr = nf * 16 + ro;
                const int c = ks * 4 + g;
                const int sch = (c ^ vr) & 7;
                bf16x8 vf = *reinterpret_cast<const bf16x8*>(&ldsV[cur][vr * 64 + sch * 8]);
                of[nf] = __builtin_amdgcn_mfma_f32_16x16x32_bf16(pa, vf, of[nf], 0, 0, 0);
            }
        }
        __builtin_amdgcn_s_setprio(0);

        asm volatile("s_waitcnt vmcnt(0)" ::: "memory");
        __syncthreads();
        cur ^= 1;
    }

    const int b = bh >> 4, h = bh & 15;
    float inv_l[4];
    #pragma unroll
    for (int r = 0; r < 4; ++r) inv_l[r] = 1.0f / lrow[r];
    #pragma unroll
    for (int r = 0; r < 4; ++r) {
        const int srow = qbase + rg + r;
        unsigned short* dst = Ao + (size_t)(srow * B_DIM + b) * D_DIM + h * C_DIM;
        #pragma unroll
        for (int nf = 0; nf < 8; ++nf)
            dst[nf * 16 + ro] = f2bf(of[nf][r] * inv_l[r]);
    }
}

extern "C" void kernel_launch(void* const* d_in, const int* in_sizes, int n_in,
                              void* d_out, int out_size, void* d_ws, size_t ws_size,
                              hipStream_t stream) {
    const float* x       = (const float*)d_in[0];
    const float* rope    = (const float*)d_in[1];
    const float* Wq      = (const float*)d_in[2];
    const float* Wk      = (const float*)d_in[3];
    const float* Wv      = (const float*)d_in[4];
    const float* Wo      = (const float*)d_in[5];
    const float* q_scale = (const float*)d_in[6];
    const float* k_scale = (const float*)d_in[7];
    float* out = (float*)d_out;

    char* w = (char*)d_ws;
    size_t off = 0;
    auto alloc = [&](size_t bytes) {
        char* p = w + off; off += (bytes + 255) & ~(size_t)255; return p;
    };
    unsigned short* xb   = (unsigned short*)alloc((size_t)M_DIM * D_DIM * 2);      // 16 MiB
    unsigned short* Wqb  = (unsigned short*)alloc((size_t)4 * D_DIM * D_DIM * 2);  // Wq|Wk|Wv|Wo contiguous
    unsigned short* Wob  = Wqb + (size_t)3 * D_DIM * D_DIM;
    unsigned short* rawQKV = (unsigned short*)alloc((size_t)M_DIM * 3 * D_DIM * 2); // [M][6144]
    unsigned short* Qb   = (unsigned short*)alloc((size_t)M_DIM * D_DIM * 2);
    unsigned short* Kb   = (unsigned short*)alloc((size_t)M_DIM * D_DIM * 2);
    unsigned short* Vt   = (unsigned short*)alloc((size_t)M_DIM * D_DIM * 2);
    float* ctab = (float*)alloc((size_t)S_DIM * C_DIM * 4);
    float* stab = (float*)alloc((size_t)S_DIM * C_DIM * 4);
    unsigned short* Ao = rawQKV;  // reuse (rawQKV dead before attention writes)
    (void)ws_size; (void)in_sizes; (void)n_in; (void)out_size;

    const int NQKV = 3 * D_DIM;  // 6144
    const float inv_scale = 0.08838834764831845f;  // 1/sqrt(128)

    rope_tables_k<<<(S_DIM * C_DIM + 255) / 256, 256, 0, stream>>>(rope, ctab, stab, S_DIM * C_DIM);
    cast_bf16_k<<<2048, 256, 0, stream>>>(x, xb, M_DIM * D_DIM / 4);
    cast_w4_k<<<2048, 256, 0, stream>>>(Wq, Wk, Wv, Wo, Wqb);

    // fused QKV projection: [4096,2048] x [6144,2048]^T  (128x256 tiles, 768 blocks)
    gemm_bn_k<unsigned short><<<dim3(M_DIM / 128, NQKV / 256), 512, 0, stream>>>(
        xb, Wqb, rawQKV, M_DIM, NQKV, D_DIM);

    qk_post_k<<<M_DIM * H_DIM / 4, 256, 0, stream>>>(rawQKV,         NQKV, q_scale, ctab, stab, Qb, inv_scale);
    qk_post_k<<<M_DIM * H_DIM / 4, 256, 0, stream>>>(rawQKV + D_DIM, NQKV, k_scale, ctab, stab, Kb, 1.0f);
    v_transpose_k<<<dim3(S_DIM / 64, B_DIM * H_DIM), 256, 0, stream>>>(rawQKV, NQKV, 2 * D_DIM, Vt);

    attn_k<<<dim3(S_DIM / 128, B_DIM * H_DIM), 512, 0, stream>>>(Qb, Kb, Vt, Ao);

    // out projection: [4096,2048] x [2048,2048]^T -> fp32 d_out  (256 blocks, exact fill)
    gemm_bn_k<float><<<dim3(M_DIM / 128, D_DIM / 256), 512, 0, stream>>>(
        Ao, Wob, out, M_DIM, D_DIM, D_DIM);
}